// Round 9
// baseline (2210.586 us; speedup 1.0000x reference)
//
#include <hip/hip_runtime.h>
#include <hip/hip_bf16.h>
#include <math.h>
#include <float.h>

#define B_ 8
#define N_ 4096
#define M_ (B_*N_)
#define KNN 10

typedef unsigned long long ull;
typedef __attribute__((ext_vector_type(8))) short s16x8;
typedef __attribute__((ext_vector_type(4))) float f32x4;

__device__ __forceinline__ float mishf(float x){
  float sp = (x > 20.f) ? x : __logf(1.f + __expf(x));
  float e2 = __expf(-2.f*sp);
  float th = (1.f - e2) / (1.f + e2);
  return x * th;
}

__device__ __forceinline__ ull shfl_xor_u64(ull v, int mask){
  unsigned lo = (unsigned)v, hi = (unsigned)(v >> 32);
  lo = (unsigned)__shfl_xor((int)lo, mask);
  hi = (unsigned)__shfl_xor((int)hi, mask);
  return ((ull)hi << 32) | lo;
}
__device__ __forceinline__ ull shfl_u64(ull v, int src){
  unsigned lo = (unsigned)v, hi = (unsigned)(v >> 32);
  lo = (unsigned)__shfl((int)lo, src);
  hi = (unsigned)__shfl((int)hi, src);
  return ((ull)hi << 32) | lo;
}
__device__ __forceinline__ int mbcnt_lt(ull mask){
  return __builtin_amdgcn_mbcnt_hi((unsigned)(mask>>32),
         __builtin_amdgcn_mbcnt_lo((unsigned)mask, 0));
}
__device__ __forceinline__ unsigned mono_u32(float f){
  unsigned u = __float_as_uint(f);
  return u ^ ((unsigned)((int)u >> 31) | 0x80000000u);
}
__device__ __forceinline__ float unmono(unsigned vk){
  unsigned u = (vk & 0x80000000u) ? (vk ^ 0x80000000u) : ~vk;
  return __uint_as_float(u);
}

// ---------------- transpose x (B,3,N) -> xp (B*N,3) ----------------
__global__ __launch_bounds__(256) void k_transpose_x(const float* __restrict__ x,
                                                     float* __restrict__ xp){
  int n = blockIdx.x*256 + threadIdx.x;
  if (n >= M_) return;
  int b = n >> 12, i = n & (N_-1);
  const float* xb = x + (size_t)b*3*N_;
  float v0 = xb[i], v1 = xb[N_+i], v2 = xb[2*N_+i];
  float* o = xp + (size_t)n*3;
  o[0]=v0; o[1]=v1; o[2]=v2;
}

// ---------------- xx[n] = sum_c X[n,c]^2 ----------------
template<int C>
__global__ __launch_bounds__(256) void k_xx(const float* __restrict__ X,
                                            float* __restrict__ xx){
  int n = blockIdx.x*256 + threadIdx.x;
  if (n >= M_) return;
  const float* r = X + (size_t)n*C;
  float s = 0.f;
#pragma unroll
  for (int c=0;c<C;c++){ float v=r[c]; s = fmaf(v,v,s); }
  xx[n] = s;
}

// ---------------- split fp32 -> bf16 hi + bf16 lo (exact 2-term split) ------
__global__ __launch_bounds__(256) void k_cvt(const float* __restrict__ X,
                                             ushort* __restrict__ Xhi,
                                             ushort* __restrict__ Xlo){
  int i = blockIdx.x*256 + threadIdx.x;
  const float4* src = (const float4*)X + (size_t)i*2;
  float4 v0 = src[0], v1 = src[1];
  float vv[8] = {v0.x,v0.y,v0.z,v0.w,v1.x,v1.y,v1.z,v1.w};
  ushort h[8], l[8];
#pragma unroll
  for (int e=0;e<8;e++){
    __hip_bfloat16 hb = __float2bfloat16(vv[e]);
    float hf = __bfloat162float(hb);
    __hip_bfloat16 lb = __float2bfloat16(vv[e]-hf);
    h[e] = *(ushort*)&hb; l[e] = *(ushort*)&lb;
  }
  uint4 hp, lp;
  hp.x = (unsigned)h[0] | ((unsigned)h[1]<<16);
  hp.y = (unsigned)h[2] | ((unsigned)h[3]<<16);
  hp.z = (unsigned)h[4] | ((unsigned)h[5]<<16);
  hp.w = (unsigned)h[6] | ((unsigned)h[7]<<16);
  lp.x = (unsigned)l[0] | ((unsigned)l[1]<<16);
  lp.y = (unsigned)l[2] | ((unsigned)l[3]<<16);
  lp.z = (unsigned)l[4] | ((unsigned)l[5]<<16);
  lp.w = (unsigned)l[6] | ((unsigned)l[7]<<16);
  *(uint4*)(Xhi + (size_t)i*8) = hp;
  *(uint4*)(Xlo + (size_t)i*8) = lp;
}

// ---------------- MFMA kNN, j-split (C=64, split-bf16 exact gram) ----------
// grid 1024: b = bid&7 (XCD pin), rest = bid>>3: i0 = (rest>>1)*64, half = rest&1.
// Each block scans 2048 j-cols (JT=64 tiles) and emits sorted top-10 u64 KEYS.
// OCCUPANCY LADDER (measured): (256,2)+grid512 = 2 blk/CU, 463us (grid-limited);
// (256,4)+grid1024 = 4 blk/CU but SPILLS (49MB WRITE_SIZE, 597us -- R8).
// (256,3): VGPR budget 170 > ~116 needed -> no spill; LDS 27KB*3=81KB -> 3 blk/CU.
__global__ __launch_bounds__(256,3) void k_knn64m(const ushort* __restrict__ Xhi,
                                                  const ushort* __restrict__ Xlo,
                                                  const float* __restrict__ xx,
                                                  ull* __restrict__ part){
  constexpr int JT  = 64;
  constexpr int CAP = 320;
  __shared__ ushort XJhi[JT*64];   // swizzled: byte (r*128 + (kbyte ^ ((r&7)<<4)))
  __shared__ ushort XJlo[JT*64];
  __shared__ float  halfxx[JT];
  __shared__ ull    buf[4][CAP];

  const int t    = threadIdx.x;
  const int w    = t >> 6;
  const int lane = t & 63;
  const int bid  = blockIdx.x;
  const int b    = bid & 7;
  const int rest = bid >> 3;
  const int i0   = (rest >> 1) * 64;
  const int half = rest & 1;
  const int jbase = half * 2048;
  const float* xxb = xx + (size_t)b*N_;

  // ---- A fragments (this wave's 16 rows) ----
  const int arow = i0 + w*16 + (lane & 15);
  const ushort* Ah = Xhi + ((size_t)(b*N_ + arow))*64;
  const ushort* Al = Xlo + ((size_t)(b*N_ + arow))*64;
  const int ko = (lane >> 4)*8;
  s16x8 aH0 = *(const s16x8*)(Ah + ko);
  s16x8 aH1 = *(const s16x8*)(Ah + 32 + ko);
  s16x8 aL0 = *(const s16x8*)(Al + ko);
  s16x8 aL1 = *(const s16x8*)(Al + 32 + ko);

  ull kq[KNN];
#pragma unroll
  for (int q=0;q<KNN;q++) kq[q]=0ull;
  float Treg = -INFINITY;

  for (int jt = 0; jt < 2048/JT; ++jt){
    const int j0g = jbase + jt*JT;
    // ---- stage XJ: 64 rows x 2 bufs, 4 uint4 per thread ----
    {
      const int bsel = t >> 7;                 // 0 hi, 1 lo
      const int r    = (t >> 1) & 63;
      const int cq   = (t & 1) * 4;            // starting uint4 index (of 8)
      const ushort* src = (bsel ? Xlo : Xhi) + ((size_t)(b*N_ + j0g + r))*64 + cq*8;
      char* dst = (char*)(bsel ? XJlo : XJhi) + r*128;
      const unsigned sw = ((unsigned)(r & 7)) << 4;
#pragma unroll
      for (int c=0;c<4;c++){
        uint4 v = *(const uint4*)(src + c*8);
        *(uint4*)(dst + ((unsigned)((cq+c)*16) ^ sw)) = v;
      }
    }
    if (t < JT) halfxx[t] = 0.5f*xxb[j0g+t];
    __syncthreads();

    // ---- gram: 4 col-blocks x 8 MFMA ----
    f32x4 acc[4];
#pragma unroll
    for (int cb=0;cb<4;cb++) acc[cb] = (f32x4){0.f,0.f,0.f,0.f};

#pragma unroll
    for (int cb=0;cb<4;cb++){
      const int brow = cb*16 + (lane & 15);
      const unsigned sw = ((unsigned)(brow & 7)) << 4;
      const char* ph = (const char*)XJhi + brow*128;
      const char* pl = (const char*)XJlo + brow*128;
      const int kb0 = (int)((unsigned)((lane>>4)<<4) ^ sw);
      const int kb1 = (int)((unsigned)(64 | ((lane>>4)<<4)) ^ sw);
      s16x8 bh0 = *(const s16x8*)(ph + kb0);
      s16x8 bl0 = *(const s16x8*)(pl + kb0);
      s16x8 bh1 = *(const s16x8*)(ph + kb1);
      s16x8 bl1 = *(const s16x8*)(pl + kb1);
      f32x4 a = acc[cb];
      a = __builtin_amdgcn_mfma_f32_16x16x32_bf16(aH0, bh0, a, 0,0,0);
      a = __builtin_amdgcn_mfma_f32_16x16x32_bf16(aH0, bl0, a, 0,0,0);
      a = __builtin_amdgcn_mfma_f32_16x16x32_bf16(aL0, bh0, a, 0,0,0);
      a = __builtin_amdgcn_mfma_f32_16x16x32_bf16(aL0, bl0, a, 0,0,0);
      a = __builtin_amdgcn_mfma_f32_16x16x32_bf16(aH1, bh1, a, 0,0,0);
      a = __builtin_amdgcn_mfma_f32_16x16x32_bf16(aH1, bl1, a, 0,0,0);
      a = __builtin_amdgcn_mfma_f32_16x16x32_bf16(aL1, bh1, a, 0,0,0);
      a = __builtin_amdgcn_mfma_f32_16x16x32_bf16(aL1, bl1, a, 0,0,0);
      acc[cb] = a;
    }

    float hx[4];
#pragma unroll
    for (int cb=0;cb<4;cb++) hx[cb] = halfxx[cb*16 + (lane & 15)];

    if (jt == 0){
      // ---- bootstrap: exact top-10 of this block's first 64 cols per row ----
#pragma unroll
      for (int reg=0;reg<4;reg++){
        const unsigned rl = (unsigned)((lane>>4)*4 + reg);
        ull k4[4];
#pragma unroll
        for (int cb=0;cb<4;cb++){
          float v = acc[cb][reg] - hx[cb];
          unsigned jinv = 4095u - (unsigned)(j0g + cb*16 + (lane & 15));
          k4[cb] = ((ull)mono_u32(v)<<32) | ((ull)jinv<<4) | rl;
        }
#pragma unroll
        for (int q=0;q<KNN;q++){
          ull m = k4[0];
#pragma unroll
          for (int s=1;s<4;s++) m = m > k4[s] ? m : k4[s];
          ull v1 = shfl_xor_u64(m,1); m = m>v1?m:v1;
          ull v2 = shfl_xor_u64(m,2); m = m>v2?m:v2;
          ull v4 = shfl_xor_u64(m,4); m = m>v4?m:v4;
          ull v8 = shfl_xor_u64(m,8); m = m>v8?m:v8;
          ull mv = shfl_u64(m, (lane>>2)<<4);
          if (lane < 16 && (lane&3)==reg) kq[q] = mv;
#pragma unroll
          for (int s=0;s<4;s++) k4[s] = (k4[s]==m) ? 0ull : k4[s];
        }
      }
      Treg = unmono((unsigned)(kq[KNN-1] >> 32));
    } else {
      // ---- filter & compact survivors ----
      float Tf[4];
#pragma unroll
      for (int reg=0;reg<4;reg++) Tf[reg] = __shfl(Treg, (lane>>4)*4 + reg);
      int cnt = 0;
#pragma unroll
      for (int cb=0;cb<4;cb++){
#pragma unroll
        for (int reg=0;reg<4;reg++){
          float v = acc[cb][reg] - hx[cb];
          bool pass = v >= Tf[reg];
          ull mask = __ballot(pass);
          if (mask){
            if (pass){
              int slot = cnt + mbcnt_lt(mask);
              unsigned jinv = 4095u - (unsigned)(j0g + cb*16 + (lane & 15));
              ull key = ((ull)mono_u32(v)<<32) | ((ull)jinv<<4)
                        | (unsigned)((lane>>4)*4 + reg);
              if (slot < CAP) buf[w][slot] = key;
            }
            cnt += __popcll(mask);
          }
        }
      }
      // ---- drain (chunks of 4: overlap ds_read latency; 0-pad never inserts) ----
      if (cnt){
        int nb = cnt < CAP ? cnt : CAP;
        int pad = (4 - (nb & 3)) & 3;
        if (lane < pad && nb + lane < CAP) buf[w][nb + lane] = 0ull;
        int nb4 = nb + pad; if (nb4 > CAP) nb4 = CAP;
        for (int e=0;e<nb4;e+=4){
          ull c0=buf[w][e+0], c1=buf[w][e+1], c2=buf[w][e+2], c3=buf[w][e+3];
#pragma unroll
          for (int u=0;u<4;u++){
            ull k64 = (u==0)?c0:(u==1)?c1:(u==2)?c2:c3;
            if ((int)(k64 & 15ull) == lane && k64 > kq[KNN-1]){
              ull ck = k64;
#pragma unroll
              for (int q=0;q<KNN;q++){
                ull hi = ck > kq[q] ? ck : kq[q];
                ull lo = ck > kq[q] ? kq[q] : ck;
                kq[q] = hi; ck = lo;
              }
            }
          }
        }
        Treg = unmono((unsigned)(kq[KNN-1] >> 32));
      }
    }
    __syncthreads();   // XJ consumed; safe to restage
  }

  if (lane < 16){
    ull* o = part + ((size_t)((b*N_ + i0 + w*16 + lane)*2 + half))*KNN;
#pragma unroll
    for (int q=0;q<KNN;q++) o[q] = kq[q];
  }
}

// ---------------- fp32 kNN, j-split (used for C=3) ----------------
template<int C>
__global__ __launch_bounds__(256,3) void k_knn(const float* __restrict__ X,
                                               const float* __restrict__ xx,
                                               ull* __restrict__ part){
  constexpr bool BIG = (C % 4 == 0);
  constexpr int LS  = BIG ? (C + 4) : 12;
  constexpr int NC4 = BIG ? (C/4 + 1) : 1;
  constexpr int JT  = 128;
  constexpr int CAP = 320;
  __shared__ float XI[64*LS];
  __shared__ float XJ[JT*LS];
  __shared__ ull   buf[4][CAP];

  const int t    = threadIdx.x;
  const int w    = t >> 6;
  const int lane = t & 63;
  const int bid  = blockIdx.x;
  const int b    = bid & 7;
  const int rest = bid >> 3;
  const int i0   = (rest >> 1) * 64;
  const int half = rest & 1;
  const int jbase = half * 2048;
  const int tc   = t & 15, tr = t >> 4;
  const float* Xb  = X  + (size_t)b*N_*C;
  const float* xxb = xx + (size_t)b*N_;

  if constexpr (BIG){
    for (int f = t; f < 64*(C/4); f += 256){
      int r = f >> 4, c4 = f & 15;
      *(float4*)&XI[r*LS + c4*4] = *(const float4*)&Xb[(size_t)(i0+r)*C + c4*4];
    }
    if (t < 64){ XI[t*LS+C]=1.f; XI[t*LS+C+1]=0.f; XI[t*LS+C+2]=0.f; XI[t*LS+C+3]=0.f; }
  } else {
    if (t < 64){
      const float* p = &Xb[(size_t)(i0+t)*C];
      XI[t*LS+0]=p[0]; XI[t*LS+1]=p[1]; XI[t*LS+2]=p[2]; XI[t*LS+3]=1.f;
    }
  }

  ull kq[KNN];
#pragma unroll
  for (int q=0;q<KNN;q++) kq[q]=0ull;
  float Treg = -INFINITY;

  for (int jt = 0; jt < 2048/JT; ++jt){
    const int j0 = jbase + jt*JT;
    if constexpr (BIG){
      for (int f = t; f < JT*(C/4); f += 256){
        int r = f >> 4, c4 = f & 15;
        *(float4*)&XJ[r*LS + c4*4] = *(const float4*)&Xb[(size_t)(j0+r)*C + c4*4];
      }
      if (t < JT){ XJ[t*LS+C] = -0.5f*xxb[j0+t]; XJ[t*LS+C+1]=0.f; XJ[t*LS+C+2]=0.f; XJ[t*LS+C+3]=0.f; }
    } else {
      if (t < JT){
        const float* p = &Xb[(size_t)(j0+t)*C];
        XJ[t*LS+0]=p[0]; XJ[t*LS+1]=p[1]; XJ[t*LS+2]=p[2]; XJ[t*LS+3]=-0.5f*xxb[j0+t];
      }
    }
    __syncthreads();

    float acc[4][8];
#pragma unroll
    for (int rr=0;rr<4;rr++)
#pragma unroll
      for (int s=0;s<8;s++) acc[rr][s]=0.f;

#pragma unroll 2
    for (int c4 = 0; c4 < NC4; ++c4){
      float4 xi0 = *(const float4*)&XI[(tr*4+0)*LS + c4*4];
      float4 xi1 = *(const float4*)&XI[(tr*4+1)*LS + c4*4];
      float4 xi2 = *(const float4*)&XI[(tr*4+2)*LS + c4*4];
      float4 xi3 = *(const float4*)&XI[(tr*4+3)*LS + c4*4];
#pragma unroll
      for (int s=0;s<8;s++){
        float4 xj = *(const float4*)&XJ[(tc+16*s)*LS + c4*4];
        float a0=acc[0][s], a1=acc[1][s], a2=acc[2][s], a3=acc[3][s];
        a0=fmaf(xi0.x,xj.x,a0); a1=fmaf(xi1.x,xj.x,a1); a2=fmaf(xi2.x,xj.x,a2); a3=fmaf(xi3.x,xj.x,a3);
        a0=fmaf(xi0.y,xj.y,a0); a1=fmaf(xi1.y,xj.y,a1); a2=fmaf(xi2.y,xj.y,a2); a3=fmaf(xi3.y,xj.y,a3);
        a0=fmaf(xi0.z,xj.z,a0); a1=fmaf(xi1.z,xj.z,a1); a2=fmaf(xi2.z,xj.z,a2); a3=fmaf(xi3.z,xj.z,a3);
        a0=fmaf(xi0.w,xj.w,a0); a1=fmaf(xi1.w,xj.w,a1); a2=fmaf(xi2.w,xj.w,a2); a3=fmaf(xi3.w,xj.w,a3);
        acc[0][s]=a0; acc[1][s]=a1; acc[2][s]=a2; acc[3][s]=a3;
      }
    }

    if (jt == 0){
#pragma unroll
      for (int rr=0;rr<4;rr++){
        const unsigned rl = (unsigned)((lane>>4)*4 + rr);
        ull k8[8];
#pragma unroll
        for (int s=0;s<8;s++){
          unsigned jinv = 4095u - (unsigned)(j0 + tc + 16*s);
          k8[s] = ((ull)mono_u32(acc[rr][s])<<32) | ((ull)jinv<<4) | rl;
        }
#pragma unroll
        for (int q=0;q<KNN;q++){
          ull m = k8[0];
#pragma unroll
          for (int s=1;s<8;s++) m = m > k8[s] ? m : k8[s];
          ull v1 = shfl_xor_u64(m,1); m = m>v1?m:v1;
          ull v2 = shfl_xor_u64(m,2); m = m>v2?m:v2;
          ull v4 = shfl_xor_u64(m,4); m = m>v4?m:v4;
          ull v8 = shfl_xor_u64(m,8); m = m>v8?m:v8;
          ull mv = shfl_u64(m, (lane>>2)<<4);
          if (lane < 16 && (lane&3)==rr) kq[q] = mv;
#pragma unroll
          for (int s=0;s<8;s++) k8[s] = (k8[s]==m) ? 0ull : k8[s];
        }
      }
      Treg = unmono((unsigned)(kq[KNN-1] >> 32));
    } else {
      float Tf[4];
#pragma unroll
      for (int rr=0;rr<4;rr++) Tf[rr] = __shfl(Treg, (lane>>4)*4 + rr);
      int cnt = 0;
#pragma unroll
      for (int s=0;s<8;s++){
#pragma unroll
        for (int rr=0;rr<4;rr++){
          bool pass = acc[rr][s] >= Tf[rr];
          ull mask = __ballot(pass);
          if (mask){
            if (pass){
              int slot = cnt + mbcnt_lt(mask);
              unsigned jinv = 4095u - (unsigned)(j0 + tc + 16*s);
              ull key = ((ull)mono_u32(acc[rr][s])<<32) | ((ull)jinv<<4)
                        | (unsigned)((lane>>4)*4 + rr);
              if (slot < CAP) buf[w][slot] = key;
            }
            cnt += __popcll(mask);
          }
        }
      }
      if (cnt){
        int nb = cnt < CAP ? cnt : CAP;
        int pad = (4 - (nb & 3)) & 3;
        if (lane < pad && nb + lane < CAP) buf[w][nb + lane] = 0ull;
        int nb4 = nb + pad; if (nb4 > CAP) nb4 = CAP;
        for (int e=0;e<nb4;e+=4){
          ull c0=buf[w][e+0], c1=buf[w][e+1], c2=buf[w][e+2], c3=buf[w][e+3];
#pragma unroll
          for (int u=0;u<4;u++){
            ull k64 = (u==0)?c0:(u==1)?c1:(u==2)?c2:c3;
            if ((int)(k64 & 15ull) == lane && k64 > kq[KNN-1]){
              ull ck = k64;
#pragma unroll
              for (int q=0;q<KNN;q++){
                ull hi = ck > kq[q] ? ck : kq[q];
                ull lo = ck > kq[q] ? kq[q] : ck;
                kq[q] = hi; ck = lo;
              }
            }
          }
        }
        Treg = unmono((unsigned)(kq[KNN-1] >> 32));
      }
    }
    __syncthreads();
  }

  if (lane < 16){
    ull* o = part + ((size_t)((b*N_ + i0 + w*16 + lane)*2 + half))*KNN;
#pragma unroll
    for (int q=0;q<KNN;q++) o[q] = kq[q];
  }
}

// ---------------- merge two sorted-10 key lists per row -> idx ----------------
__global__ __launch_bounds__(256) void k_knnmerge(const ull* __restrict__ part,
                                                  int* __restrict__ idxout){
  int row = blockIdx.x*256 + threadIdx.x;
  if (row >= M_) return;
  const ull* pa = part + (size_t)row*2*KNN;
  const ull* pb = pa + KNN;
  int ia=0, ib=0;
  int* o = idxout + (size_t)row*KNN;
#pragma unroll
  for (int s=0;s<KNN;s++){
    ull ka = (ia < KNN) ? pa[ia] : 0ull;
    ull kb = (ib < KNN) ? pb[ib] : 0ull;
    bool ta = ka > kb;
    ull k = ta ? ka : kb;
    o[s] = (int)(4095u - (unsigned)((k>>4) & 4095ull));
    ia += ta ? 1 : 0; ib += ta ? 0 : 1;
  }
}

// ---------------- generic GEMM: Y(M x Pfull) = act(s*(X1@Wa + X2@Wb)+b) ----------
template<int PT>
__global__ __launch_bounds__(256) void k_gemm(
    const float* __restrict__ X1, int C1,
    const float* __restrict__ X2, int C2,
    const float* __restrict__ W, int hmask, int hshift, int wstride, int hoff,
    const float* __restrict__ g, const float* __restrict__ bb, int act,
    float* __restrict__ Y, int Pfull)
{
  constexpr int CPT = PT/16;
  constexpr int WLS = PT + 4;
  __shared__ float Xt[32*68];
  __shared__ float Wt[32*WLS];
  const int t  = threadIdx.x;
  const int r0 = blockIdx.x*64;
  const int p0 = blockIdx.y*PT;
  const int cg = t & 15, rg = t >> 4;
  const int C = C1 + C2;
  const int nkt = (C + 31) >> 5;

  float acc[4][CPT];
#pragma unroll
  for (int a=0;a<4;a++)
#pragma unroll
    for (int c=0;c<CPT;c++) acc[a][c]=0.f;

  for (int kt = 0; kt < nkt; ++kt){
    const int k0 = kt*32;
#pragma unroll
    for (int e = t; e < 64*32; e += 256){
      int kk = e & 31, r = e >> 5;
      int gk = k0 + kk;
      float v = 0.f;
      if (gk < C1) v = X1[(size_t)(r0+r)*C1 + gk];
      else if (gk < C) v = X2[(size_t)(r0+r)*C2 + (gk - C1)];
      Xt[kk*68 + r] = v;
    }
#pragma unroll
    for (int e = t; e < PT*32; e += 256){
      int kk = e & 31, p = e >> 5;
      int gp = p0 + p;
      int wrow = (gp & hmask)*wstride + (gp >> hshift)*hoff;
      int gk = k0 + kk;
      Wt[kk*WLS + p] = (gk < C) ? W[(size_t)wrow + gk] : 0.f;
    }
    __syncthreads();
#pragma unroll
    for (int kk=0;kk<32;kk++){
      float4 xv = *(const float4*)&Xt[kk*68 + rg*4];
      float xr[4] = {xv.x, xv.y, xv.z, xv.w};
      float wv[CPT];
#pragma unroll
      for (int c4=0;c4<CPT/4;c4++){
        float4 w4 = *(const float4*)&Wt[kk*WLS + cg*CPT + c4*4];
        wv[c4*4+0]=w4.x; wv[c4*4+1]=w4.y; wv[c4*4+2]=w4.z; wv[c4*4+3]=w4.w;
      }
#pragma unroll
      for (int rr=0;rr<4;rr++)
#pragma unroll
        for (int cc=0;cc<CPT;cc++)
          acc[rr][cc] = fmaf(xr[rr], wv[cc], acc[rr][cc]);
    }
    __syncthreads();
  }

  const float srs = rsqrtf(1.f + 1e-5f);
  float sv[CPT], bvv[CPT];
#pragma unroll
  for (int cc=0;cc<CPT;cc++){
    int gp = p0 + cg*CPT + cc;
    if (g){ sv[cc] = g[gp]*srs; bvv[cc] = bb[gp]; } else { sv[cc]=1.f; bvv[cc]=0.f; }
  }
#pragma unroll
  for (int rr=0;rr<4;rr++){
    size_t row = r0 + rg*4 + rr;
    float* yr = Y + row*(size_t)Pfull + p0 + cg*CPT;
#pragma unroll
    for (int c4=0;c4<CPT/4;c4++){
      float y0 = sv[c4*4+0]*acc[rr][c4*4+0] + bvv[c4*4+0];
      float y1 = sv[c4*4+1]*acc[rr][c4*4+1] + bvv[c4*4+1];
      float y2 = sv[c4*4+2]*acc[rr][c4*4+2] + bvv[c4*4+2];
      float y3 = sv[c4*4+3]*acc[rr][c4*4+3] + bvv[c4*4+3];
      if (act){ y0=mishf(y0); y1=mishf(y1); y2=mishf(y2); y3=mishf(y3); }
      *(float4*)&yr[c4*4] = make_float4(y0,y1,y2,y3);
    }
  }
}

// ---------------- edge gather + BN + mish + max over k ----------------
template<int O>
__global__ __launch_bounds__(256) void k_edgemax(
    const float* __restrict__ ua, const int* __restrict__ idx,
    const float* __restrict__ g, const float* __restrict__ bb,
    float* __restrict__ Y)
{
  constexpr int TPR = O/4;
  const int gt = blockIdx.x*256 + threadIdx.x;
  const int m  = gt / TPR;
  const int og = gt % TPR;
  if (m >= M_) return;
  const int base = m & ~(N_-1);
  const int P = 2*O;
  const float4 u0 = *(const float4*)&ua[(size_t)m*P + og*4];
  const float4 a0 = *(const float4*)&ua[(size_t)m*P + O + og*4];
  const float srs = rsqrtf(1.f + 1e-5f);
  const float4 gv  = *(const float4*)&g[og*4];
  const float4 bv4 = *(const float4*)&bb[og*4];
  const float sx = gv.x*srs, sy = gv.y*srs, sz = gv.z*srs, sw = gv.w*srs;
  const float cx = a0.x - u0.x, cy = a0.y - u0.y, cz = a0.z - u0.z, cw = a0.w - u0.w;
  float mx = -INFINITY, my = -INFINITY, mz = -INFINITY, mw = -INFINITY;
  const int* id = idx + (size_t)m*KNN;
#pragma unroll
  for (int k=0;k<KNN;k++){
    int j = id[k];
    const float4 uj = *(const float4*)&ua[(size_t)(base + j)*P + og*4];
    float zx = fmaf(sx, uj.x + cx, bv4.x);
    float zy = fmaf(sy, uj.y + cy, bv4.y);
    float zz = fmaf(sz, uj.z + cz, bv4.z);
    float zw = fmaf(sw, uj.w + cw, bv4.w);
    mx = fmaxf(mx, mishf(zx));
    my = fmaxf(my, mishf(zy));
    mz = fmaxf(mz, mishf(zz));
    mw = fmaxf(mw, mishf(zw));
  }
  *(float4*)&Y[(size_t)m*O + og*4] = make_float4(mx,my,mz,mw);
}

// ---------------- final projection: out(B,2,N) = W9 @ h8 ----------------
__global__ __launch_bounds__(256) void k_final(const float* __restrict__ h,
                                               const float* __restrict__ W9,
                                               float* __restrict__ out){
  __shared__ float w[128];
  const int t = threadIdx.x;
  if (t < 128) w[t] = W9[t];
  __syncthreads();
  const int m = blockIdx.x*256 + t;
  if (m >= M_) return;
  const int b = m >> 12, i = m & (N_-1);
  const float* hr = h + (size_t)m*64;
  float s0 = 0.f, s1 = 0.f;
#pragma unroll
  for (int c=0;c<64;c++){ float v = hr[c]; s0 = fmaf(w[c], v, s0); s1 = fmaf(w[64+c], v, s1); }
  out[((size_t)b*2 + 0)*N_ + i] = s0;
  out[((size_t)b*2 + 1)*N_ + i] = s1;
}

extern "C" void kernel_launch(void* const* d_in, const int* in_sizes, int n_in,
                              void* d_out, int out_size, void* d_ws, size_t ws_size,
                              hipStream_t stream)
{
  const float* x  = (const float*)d_in[0];
  const float* W1 = (const float*)d_in[1];
  const float* W2 = (const float*)d_in[2];
  const float* W3 = (const float*)d_in[3];
  const float* W4 = (const float*)d_in[4];
  const float* W5 = (const float*)d_in[5];
  const float* W6 = (const float*)d_in[6];
  const float* W7 = (const float*)d_in[7];
  const float* W8 = (const float*)d_in[8];
  const float* W9 = (const float*)d_in[9];
  const float* g1 = (const float*)d_in[10]; const float* b1 = (const float*)d_in[11];
  const float* g2 = (const float*)d_in[12]; const float* b2 = (const float*)d_in[13];
  const float* g3 = (const float*)d_in[14]; const float* b3 = (const float*)d_in[15];
  const float* g4 = (const float*)d_in[16]; const float* b4 = (const float*)d_in[17];
  const float* g5 = (const float*)d_in[18]; const float* b5 = (const float*)d_in[19];
  const float* g6 = (const float*)d_in[20]; const float* b6 = (const float*)d_in[21];
  const float* g7 = (const float*)d_in[22]; const float* b7 = (const float*)d_in[23];
  const float* g8 = (const float*)d_in[24]; const float* b8 = (const float*)d_in[25];
  float* out = (float*)d_out;

  float* ws  = (float*)d_ws;
  float* xp  = ws;                       // 98304
  float* xx  = xp + 98304;               // 32768
  int*   idx = (int*)(xx + 32768);       // 327680 ints
  float* ua  = (float*)(idx + 327680);   // 8388608 floats (max M*256)
  float* x1  = ua + 8388608;             // M*64
  float* x2  = x1 + 2097152;             // M*64
  float* x3  = x2 + 2097152;             // M*128
  float* h4  = x3 + 4194304;             // M*128
  float* h5  = h4 + 4194304;             // M*128
  float* h6  = x3;
  float* h7  = h4;
  float* h8  = h5;
  // aliases into the (dead-during-kNN) ua region:
  ushort* Xhi = (ushort*)ua;             // M*64 ushorts = 1M floats
  ushort* Xlo = (ushort*)(ua + 1048576); // M*64 ushorts
  ull*    part = (ull*)(ua + 2097152);   // M*2*10 u64 = 1.31M floats (dead before gemm)

  const dim3 blk(256);
  const float* nullf = nullptr;

  // ---- stage 1 (C=3 -> 64) ----
  k_transpose_x<<<dim3(M_/256), blk, 0, stream>>>(x, xp);
  k_xx<3><<<dim3(M_/256), blk, 0, stream>>>(xp, xx);
  k_knn<3><<<dim3(1024), blk, 0, stream>>>(xp, xx, part);
  k_knnmerge<<<dim3(M_/256), blk, 0, stream>>>(part, idx);
  k_gemm<128><<<dim3(M_/64, 1), blk, 0, stream>>>(xp, 3, nullf, 0,
      W1, 63, 6, 6, 3, nullf, nullf, 0, ua, 128);
  k_edgemax<64><<<dim3(M_*16/256), blk, 0, stream>>>(ua, idx, g1, b1, x1);

  // ---- stage 2 (64 -> 64) ----
  k_xx<64><<<dim3(M_/256), blk, 0, stream>>>(x1, xx);
  k_cvt<<<dim3(M_*64/(8*256)), blk, 0, stream>>>(x1, Xhi, Xlo);
  k_knn64m<<<dim3(1024), blk, 0, stream>>>(Xhi, Xlo, xx, part);
  k_knnmerge<<<dim3(M_/256), blk, 0, stream>>>(part, idx);
  k_gemm<128><<<dim3(M_/64, 1), blk, 0, stream>>>(x1, 64, nullf, 0,
      W2, 63, 6, 128, 64, nullf, nullf, 0, ua, 128);
  k_edgemax<64><<<dim3(M_*16/256), blk, 0, stream>>>(ua, idx, g2, b2, x2);

  // ---- stage 3 (64 -> 128) ----
  k_xx<64><<<dim3(M_/256), blk, 0, stream>>>(x2, xx);
  k_cvt<<<dim3(M_*64/(8*256)), blk, 0, stream>>>(x2, Xhi, Xlo);
  k_knn64m<<<dim3(1024), blk, 0, stream>>>(Xhi, Xlo, xx, part);
  k_knnmerge<<<dim3(M_/256), blk, 0, stream>>>(part, idx);
  k_gemm<128><<<dim3(M_/64, 2), blk, 0, stream>>>(x2, 64, nullf, 0,
      W3, 127, 7, 128, 64, nullf, nullf, 0, ua, 256);
  k_edgemax<128><<<dim3(M_*32/256), blk, 0, stream>>>(ua, idx, g3, b3, x3);

  // ---- MLP head ----
  k_gemm<128><<<dim3(M_/64, 1), blk, 0, stream>>>(x3, 128, nullf, 0,
      W4, 127, 7, 128, 0, g4, b4, 1, h4, 128);
  k_gemm<128><<<dim3(M_/64, 1), blk, 0, stream>>>(h4, 128, x3, 128,
      W5, 127, 7, 256, 0, g5, b5, 1, h5, 128);
  k_gemm<64><<<dim3(M_/64, 1), blk, 0, stream>>>(h5, 128, nullf, 0,
      W6, 63, 6, 128, 0, g6, b6, 1, h6, 64);
  k_gemm<64><<<dim3(M_/64, 1), blk, 0, stream>>>(h6, 64, x2, 64,
      W7, 63, 6, 128, 0, g7, b7, 1, h7, 64);
  k_gemm<64><<<dim3(M_/64, 1), blk, 0, stream>>>(h7, 64, x1, 64,
      W8, 63, 6, 128, 0, g8, b8, 1, h8, 64);
  k_final<<<dim3(M_/256), blk, 0, stream>>>(h8, W9, out);
}

// Round 10
// 1617.153 us; speedup vs baseline: 1.3670x; 1.3670x over previous
//
#include <hip/hip_runtime.h>
#include <hip/hip_bf16.h>
#include <math.h>
#include <float.h>

#define B_ 8
#define N_ 4096
#define M_ (B_*N_)
#define KNN 10

typedef unsigned long long ull;
typedef __attribute__((ext_vector_type(8))) short s16x8;
typedef __attribute__((ext_vector_type(4))) float f32x4;

__device__ __forceinline__ float mishf(float x){
  float sp = (x > 20.f) ? x : __logf(1.f + __expf(x));
  float e2 = __expf(-2.f*sp);
  float th = (1.f - e2) / (1.f + e2);
  return x * th;
}

__device__ __forceinline__ ull shfl_xor_u64(ull v, int mask){
  unsigned lo = (unsigned)v, hi = (unsigned)(v >> 32);
  lo = (unsigned)__shfl_xor((int)lo, mask);
  hi = (unsigned)__shfl_xor((int)hi, mask);
  return ((ull)hi << 32) | lo;
}
__device__ __forceinline__ ull shfl_u64(ull v, int src){
  unsigned lo = (unsigned)v, hi = (unsigned)(v >> 32);
  lo = (unsigned)__shfl((int)lo, src);
  hi = (unsigned)__shfl((int)hi, src);
  return ((ull)hi << 32) | lo;
}
__device__ __forceinline__ int mbcnt_lt(ull mask){
  return __builtin_amdgcn_mbcnt_hi((unsigned)(mask>>32),
         __builtin_amdgcn_mbcnt_lo((unsigned)mask, 0));
}
__device__ __forceinline__ unsigned mono_u32(float f){
  unsigned u = __float_as_uint(f);
  return u ^ ((unsigned)((int)u >> 31) | 0x80000000u);
}
__device__ __forceinline__ float unmono(unsigned vk){
  unsigned u = (vk & 0x80000000u) ? (vk ^ 0x80000000u) : ~vk;
  return __uint_as_float(u);
}

// ---------------- transpose x (B,3,N) -> xp (B*N,3) ----------------
__global__ __launch_bounds__(256) void k_transpose_x(const float* __restrict__ x,
                                                     float* __restrict__ xp){
  int n = blockIdx.x*256 + threadIdx.x;
  if (n >= M_) return;
  int b = n >> 12, i = n & (N_-1);
  const float* xb = x + (size_t)b*3*N_;
  float v0 = xb[i], v1 = xb[N_+i], v2 = xb[2*N_+i];
  float* o = xp + (size_t)n*3;
  o[0]=v0; o[1]=v1; o[2]=v2;
}

// ---------------- xx[n] = sum_c X[n,c]^2 ----------------
template<int C>
__global__ __launch_bounds__(256) void k_xx(const float* __restrict__ X,
                                            float* __restrict__ xx){
  int n = blockIdx.x*256 + threadIdx.x;
  if (n >= M_) return;
  const float* r = X + (size_t)n*C;
  float s = 0.f;
#pragma unroll
  for (int c=0;c<C;c++){ float v=r[c]; s = fmaf(v,v,s); }
  xx[n] = s;
}

// ---------------- split fp32 -> bf16 hi + bf16 lo (exact 2-term split) ------
__global__ __launch_bounds__(256) void k_cvt(const float* __restrict__ X,
                                             ushort* __restrict__ Xhi,
                                             ushort* __restrict__ Xlo){
  int i = blockIdx.x*256 + threadIdx.x;
  const float4* src = (const float4*)X + (size_t)i*2;
  float4 v0 = src[0], v1 = src[1];
  float vv[8] = {v0.x,v0.y,v0.z,v0.w,v1.x,v1.y,v1.z,v1.w};
  ushort h[8], l[8];
#pragma unroll
  for (int e=0;e<8;e++){
    __hip_bfloat16 hb = __float2bfloat16(vv[e]);
    float hf = __bfloat162float(hb);
    __hip_bfloat16 lb = __float2bfloat16(vv[e]-hf);
    h[e] = *(ushort*)&hb; l[e] = *(ushort*)&lb;
  }
  uint4 hp, lp;
  hp.x = (unsigned)h[0] | ((unsigned)h[1]<<16);
  hp.y = (unsigned)h[2] | ((unsigned)h[3]<<16);
  hp.z = (unsigned)h[4] | ((unsigned)h[5]<<16);
  hp.w = (unsigned)h[6] | ((unsigned)h[7]<<16);
  lp.x = (unsigned)l[0] | ((unsigned)l[1]<<16);
  lp.y = (unsigned)l[2] | ((unsigned)l[3]<<16);
  lp.z = (unsigned)l[4] | ((unsigned)l[5]<<16);
  lp.w = (unsigned)l[6] | ((unsigned)l[7]<<16);
  *(uint4*)(Xhi + (size_t)i*8) = hp;
  *(uint4*)(Xlo + (size_t)i*8) = lp;
}

// ---------------- MFMA kNN (C=64, split-bf16 exact gram), T14 double-buffer ---
// R7 config restored (grid 512, full j-scan, (256,2) = no spill), plus:
// - LDS double-buffer (2 x 32KB) + register staging: next tile's global loads are
//   issued BEFORE the gram (latency hides under MFMA), ds_written after it.
// - ONE barrier per tile (was 2).
// R8/R9 lesson: pushing past 2 blk/CU spills (~116 live VGPR + MFMA ops); the
// occupancy ladder (256,2)->(256,4)/(256,3) measured 463 -> 597/680us. Stay at 2.
__global__ __launch_bounds__(256,2) void k_knn64m(const ushort* __restrict__ Xhi,
                                                  const ushort* __restrict__ Xlo,
                                                  const float* __restrict__ xx,
                                                  int* __restrict__ idxout){
  constexpr int JT  = 128;
  constexpr int CAP = 320;
  __shared__ ushort XJhi[2][JT*64];   // swizzled: byte (r*128 + (kbyte ^ ((r&7)<<4)))
  __shared__ ushort XJlo[2][JT*64];
  __shared__ float  halfxx[2][JT];
  __shared__ ull    buf[4][CAP];

  const int t    = threadIdx.x;
  const int w    = t >> 6;
  const int lane = t & 63;
  const int b    = blockIdx.x & 7;          // XCD-swizzle: batch per XCD
  const int i0   = (blockIdx.x >> 3) * 64;
  const float* xxb = xx + (size_t)b*N_;

  // ---- A fragments (this wave's 16 rows) ----
  const int arow = i0 + w*16 + (lane & 15);
  const ushort* Ah = Xhi + ((size_t)(b*N_ + arow))*64;
  const ushort* Al = Xlo + ((size_t)(b*N_ + arow))*64;
  const int ko = (lane >> 4)*8;
  s16x8 aH0 = *(const s16x8*)(Ah + ko);
  s16x8 aH1 = *(const s16x8*)(Ah + 32 + ko);
  s16x8 aL0 = *(const s16x8*)(Al + ko);
  s16x8 aL1 = *(const s16x8*)(Al + 32 + ko);

  ull kq[KNN];
#pragma unroll
  for (int q=0;q<KNN;q++) kq[q]=0ull;
  float Treg = -INFINITY;

  // staging assignment: thread t stages row sr=t&127 of (t<128 ? hi : lo)
  const int sr = t & 127;
  const ushort* sbase = ((t < 128) ? Xhi : Xlo) + ((size_t)(b*N_))*64;
  const unsigned ssw = ((unsigned)(sr & 7)) << 4;

  uint4 stg[8]; float hstg = 0.f;
  // prologue: stage tile 0
  {
    const ushort* src = sbase + ((size_t)sr)*64;
#pragma unroll
    for (int c=0;c<8;c++) stg[c] = *(const uint4*)(src + c*8);
    if (t < JT) hstg = 0.5f*xxb[t];
    char* dst = (char*)((t < 128) ? XJhi[0] : XJlo[0]) + sr*128;
#pragma unroll
    for (int c=0;c<8;c++) *(uint4*)(dst + ((unsigned)(c*16) ^ ssw)) = stg[c];
    if (t < JT) halfxx[0][t] = hstg;
  }
  __syncthreads();

  for (int jt = 0; jt < N_/JT; ++jt){
    const int cur = jt & 1;
    const int j0 = jt*JT;

    // ---- issue next tile's global loads (latency hides under gram) ----
    if (jt < N_/JT - 1){
      const ushort* src = sbase + ((size_t)(j0 + JT + sr))*64;
#pragma unroll
      for (int c=0;c<8;c++) stg[c] = *(const uint4*)(src + c*8);
      if (t < JT) hstg = 0.5f*xxb[j0 + JT + t];
    }

    // ---- gram: 8 col-blocks x (2 khalf x 4 products) MFMA on buffer cur ----
    f32x4 acc[8];
#pragma unroll
    for (int cb=0;cb<8;cb++) acc[cb] = (f32x4){0.f,0.f,0.f,0.f};

#pragma unroll
    for (int cb=0;cb<8;cb++){
      const int brow = cb*16 + (lane & 15);
      const unsigned sw = ((unsigned)(brow & 7)) << 4;
      const char* ph = (const char*)XJhi[cur] + brow*128;
      const char* pl = (const char*)XJlo[cur] + brow*128;
      const int kb0 = (int)((unsigned)((lane>>4)<<4) ^ sw);
      const int kb1 = (int)((unsigned)(64 | ((lane>>4)<<4)) ^ sw);
      s16x8 bh0 = *(const s16x8*)(ph + kb0);
      s16x8 bl0 = *(const s16x8*)(pl + kb0);
      s16x8 bh1 = *(const s16x8*)(ph + kb1);
      s16x8 bl1 = *(const s16x8*)(pl + kb1);
      f32x4 a = acc[cb];
      a = __builtin_amdgcn_mfma_f32_16x16x32_bf16(aH0, bh0, a, 0,0,0);
      a = __builtin_amdgcn_mfma_f32_16x16x32_bf16(aH0, bl0, a, 0,0,0);
      a = __builtin_amdgcn_mfma_f32_16x16x32_bf16(aL0, bh0, a, 0,0,0);
      a = __builtin_amdgcn_mfma_f32_16x16x32_bf16(aL0, bl0, a, 0,0,0);
      a = __builtin_amdgcn_mfma_f32_16x16x32_bf16(aH1, bh1, a, 0,0,0);
      a = __builtin_amdgcn_mfma_f32_16x16x32_bf16(aH1, bl1, a, 0,0,0);
      a = __builtin_amdgcn_mfma_f32_16x16x32_bf16(aL1, bh1, a, 0,0,0);
      a = __builtin_amdgcn_mfma_f32_16x16x32_bf16(aL1, bl1, a, 0,0,0);
      acc[cb] = a;
    }

    float hx[8];
#pragma unroll
    for (int cb=0;cb<8;cb++) hx[cb] = halfxx[cur][cb*16 + (lane & 15)];

    // ---- write staged tile jt+1 into the other buffer (no hazard w/ cur reads) ----
    if (jt < N_/JT - 1){
      char* dst = (char*)((t < 128) ? XJhi[cur^1] : XJlo[cur^1]) + sr*128;
#pragma unroll
      for (int c=0;c<8;c++) *(uint4*)(dst + ((unsigned)(c*16) ^ ssw)) = stg[c];
      if (t < JT) halfxx[cur^1][t] = hstg;
    }

    if (jt == 0){
      // ---- bootstrap: exact top-10 of first 128 cols per row ----
#pragma unroll
      for (int reg=0;reg<4;reg++){
        const unsigned rl = (unsigned)((lane>>4)*4 + reg);
        ull k8[8];
#pragma unroll
        for (int cb=0;cb<8;cb++){
          float v = acc[cb][reg] - hx[cb];
          unsigned jinv = 4095u - (unsigned)(cb*16 + (lane & 15));
          k8[cb] = ((ull)mono_u32(v)<<32) | ((ull)jinv<<4) | rl;
        }
#pragma unroll
        for (int q=0;q<KNN;q++){
          ull m = k8[0];
#pragma unroll
          for (int s=1;s<8;s++) m = m > k8[s] ? m : k8[s];
          ull v1 = shfl_xor_u64(m,1); m = m>v1?m:v1;
          ull v2 = shfl_xor_u64(m,2); m = m>v2?m:v2;
          ull v4 = shfl_xor_u64(m,4); m = m>v4?m:v4;
          ull v8 = shfl_xor_u64(m,8); m = m>v8?m:v8;
          ull mv = shfl_u64(m, (lane>>2)<<4);
          if (lane < 16 && (lane&3)==reg) kq[q] = mv;
#pragma unroll
          for (int s=0;s<8;s++) k8[s] = (k8[s]==m) ? 0ull : k8[s];
        }
      }
      Treg = unmono((unsigned)(kq[KNN-1] >> 32));
    } else {
      // ---- filter & compact survivors ----
      float Tf[4];
#pragma unroll
      for (int reg=0;reg<4;reg++) Tf[reg] = __shfl(Treg, (lane>>4)*4 + reg);
      int cnt = 0;
#pragma unroll
      for (int cb=0;cb<8;cb++){
#pragma unroll
        for (int reg=0;reg<4;reg++){
          float v = acc[cb][reg] - hx[cb];
          bool pass = v >= Tf[reg];
          ull mask = __ballot(pass);
          if (mask){
            if (pass){
              int slot = cnt + mbcnt_lt(mask);
              unsigned jinv = 4095u - (unsigned)(j0 + cb*16 + (lane & 15));
              ull key = ((ull)mono_u32(v)<<32) | ((ull)jinv<<4)
                        | (unsigned)((lane>>4)*4 + reg);
              if (slot < CAP) buf[w][slot] = key;
            }
            cnt += __popcll(mask);
          }
        }
      }
      // ---- drain (chunks of 4: overlap ds_read latency; 0-pad never inserts) ----
      if (cnt){
        int nb = cnt < CAP ? cnt : CAP;
        int pad = (4 - (nb & 3)) & 3;
        if (lane < pad && nb + lane < CAP) buf[w][nb + lane] = 0ull;
        int nb4 = nb + pad; if (nb4 > CAP) nb4 = CAP;
        for (int e=0;e<nb4;e+=4){
          ull c0=buf[w][e+0], c1=buf[w][e+1], c2=buf[w][e+2], c3=buf[w][e+3];
#pragma unroll
          for (int u=0;u<4;u++){
            ull k64 = (u==0)?c0:(u==1)?c1:(u==2)?c2:c3;
            if ((int)(k64 & 15ull) == lane && k64 > kq[KNN-1]){
              ull ck = k64;
#pragma unroll
              for (int q=0;q<KNN;q++){
                ull hi = ck > kq[q] ? ck : kq[q];
                ull lo = ck > kq[q] ? kq[q] : ck;
                kq[q] = hi; ck = lo;
              }
            }
          }
        }
        Treg = unmono((unsigned)(kq[KNN-1] >> 32));
      }
    }
    __syncthreads();   // buffers swap; drain buf reuse safe
  }

  if (lane < 16){
    int* o = idxout + ((size_t)b*N_ + i0 + w*16 + lane)*KNN;
#pragma unroll
    for (int q=0;q<KNN;q++) o[q] = (int)(4095u - (unsigned)((kq[q]>>4) & 4095ull));
  }
}

// ---------------- fp32 kNN (kept for C=3 stage) -- R7 config ----------------
template<int C>
__global__ __launch_bounds__(256,2) void k_knn(const float* __restrict__ X,
                                               const float* __restrict__ xx,
                                               int* __restrict__ idxout){
  constexpr bool BIG = (C % 4 == 0);
  constexpr int LS  = BIG ? (C + 4) : 12;
  constexpr int NC4 = BIG ? (C/4 + 1) : 1;
  constexpr int JT  = 128;
  constexpr int CAP = 320;
  __shared__ float XI[64*LS];
  __shared__ float XJ[JT*LS];
  __shared__ ull   buf[4][CAP];

  const int t    = threadIdx.x;
  const int w    = t >> 6;
  const int lane = t & 63;
  const int b    = blockIdx.y;
  const int i0   = blockIdx.x*64;
  const int tc   = t & 15, tr = t >> 4;
  const float* Xb  = X  + (size_t)b*N_*C;
  const float* xxb = xx + (size_t)b*N_;

  if constexpr (BIG){
    for (int f = t; f < 64*(C/4); f += 256){
      int r = f >> 4, c4 = f & 15;
      *(float4*)&XI[r*LS + c4*4] = *(const float4*)&Xb[(size_t)(i0+r)*C + c4*4];
    }
    if (t < 64){ XI[t*LS+C]=1.f; XI[t*LS+C+1]=0.f; XI[t*LS+C+2]=0.f; XI[t*LS+C+3]=0.f; }
  } else {
    if (t < 64){
      const float* p = &Xb[(size_t)(i0+t)*C];
      XI[t*LS+0]=p[0]; XI[t*LS+1]=p[1]; XI[t*LS+2]=p[2]; XI[t*LS+3]=1.f;
    }
  }

  ull kq[KNN];
#pragma unroll
  for (int q=0;q<KNN;q++) kq[q]=0ull;
  float Treg = -INFINITY;

  for (int jt = 0; jt < N_/JT; ++jt){
    const int j0 = jt*JT;
    if constexpr (BIG){
      for (int f = t; f < JT*(C/4); f += 256){
        int r = f >> 4, c4 = f & 15;
        *(float4*)&XJ[r*LS + c4*4] = *(const float4*)&Xb[(size_t)(j0+r)*C + c4*4];
      }
      if (t < JT){ XJ[t*LS+C] = -0.5f*xxb[j0+t]; XJ[t*LS+C+1]=0.f; XJ[t*LS+C+2]=0.f; XJ[t*LS+C+3]=0.f; }
    } else {
      if (t < JT){
        const float* p = &Xb[(size_t)(j0+t)*C];
        XJ[t*LS+0]=p[0]; XJ[t*LS+1]=p[1]; XJ[t*LS+2]=p[2]; XJ[t*LS+3]=-0.5f*xxb[j0+t];
      }
    }
    __syncthreads();

    float acc[4][8];
#pragma unroll
    for (int rr=0;rr<4;rr++)
#pragma unroll
      for (int s=0;s<8;s++) acc[rr][s]=0.f;

#pragma unroll 2
    for (int c4 = 0; c4 < NC4; ++c4){
      float4 xi0 = *(const float4*)&XI[(tr*4+0)*LS + c4*4];
      float4 xi1 = *(const float4*)&XI[(tr*4+1)*LS + c4*4];
      float4 xi2 = *(const float4*)&XI[(tr*4+2)*LS + c4*4];
      float4 xi3 = *(const float4*)&XI[(tr*4+3)*LS + c4*4];
#pragma unroll
      for (int s=0;s<8;s++){
        float4 xj = *(const float4*)&XJ[(tc+16*s)*LS + c4*4];
        float a0=acc[0][s], a1=acc[1][s], a2=acc[2][s], a3=acc[3][s];
        a0=fmaf(xi0.x,xj.x,a0); a1=fmaf(xi1.x,xj.x,a1); a2=fmaf(xi2.x,xj.x,a2); a3=fmaf(xi3.x,xj.x,a3);
        a0=fmaf(xi0.y,xj.y,a0); a1=fmaf(xi1.y,xj.y,a1); a2=fmaf(xi2.y,xj.y,a2); a3=fmaf(xi3.y,xj.y,a3);
        a0=fmaf(xi0.z,xj.z,a0); a1=fmaf(xi1.z,xj.z,a1); a2=fmaf(xi2.z,xj.z,a2); a3=fmaf(xi3.z,xj.z,a3);
        a0=fmaf(xi0.w,xj.w,a0); a1=fmaf(xi1.w,xj.w,a1); a2=fmaf(xi2.w,xj.w,a2); a3=fmaf(xi3.w,xj.w,a3);
        acc[0][s]=a0; acc[1][s]=a1; acc[2][s]=a2; acc[3][s]=a3;
      }
    }

    if (jt == 0){
#pragma unroll
      for (int rr=0;rr<4;rr++){
        const unsigned rl = (unsigned)((lane>>4)*4 + rr);
        ull k8[8];
#pragma unroll
        for (int s=0;s<8;s++){
          unsigned jinv = 4095u - (unsigned)(tc + 16*s);
          k8[s] = ((ull)mono_u32(acc[rr][s])<<32) | ((ull)jinv<<4) | rl;
        }
#pragma unroll
        for (int q=0;q<KNN;q++){
          ull m = k8[0];
#pragma unroll
          for (int s=1;s<8;s++) m = m > k8[s] ? m : k8[s];
          ull v1 = shfl_xor_u64(m,1); m = m>v1?m:v1;
          ull v2 = shfl_xor_u64(m,2); m = m>v2?m:v2;
          ull v4 = shfl_xor_u64(m,4); m = m>v4?m:v4;
          ull v8 = shfl_xor_u64(m,8); m = m>v8?m:v8;
          ull mv = shfl_u64(m, (lane>>2)<<4);
          if (lane < 16 && (lane&3)==rr) kq[q] = mv;
#pragma unroll
          for (int s=0;s<8;s++) k8[s] = (k8[s]==m) ? 0ull : k8[s];
        }
      }
      Treg = unmono((unsigned)(kq[KNN-1] >> 32));
    } else {
      float Tf[4];
#pragma unroll
      for (int rr=0;rr<4;rr++) Tf[rr] = __shfl(Treg, (lane>>4)*4 + rr);
      int cnt = 0;
#pragma unroll
      for (int s=0;s<8;s++){
#pragma unroll
        for (int rr=0;rr<4;rr++){
          bool pass = acc[rr][s] >= Tf[rr];
          ull mask = __ballot(pass);
          if (mask){
            if (pass){
              int slot = cnt + mbcnt_lt(mask);
              unsigned jinv = 4095u - (unsigned)(j0 + tc + 16*s);
              ull key = ((ull)mono_u32(acc[rr][s])<<32) | ((ull)jinv<<4)
                        | (unsigned)((lane>>4)*4 + rr);
              if (slot < CAP) buf[w][slot] = key;
            }
            cnt += __popcll(mask);
          }
        }
      }
      if (cnt){
        int nb = cnt < CAP ? cnt : CAP;
        for (int e=0;e<nb;e++){
          ull k64 = buf[w][e];
          if ((int)(k64 & 15ull) == lane && k64 > kq[KNN-1]){
            ull ck = k64;
#pragma unroll
            for (int q=0;q<KNN;q++){
              ull hi = ck > kq[q] ? ck : kq[q];
              ull lo = ck > kq[q] ? kq[q] : ck;
              kq[q] = hi; ck = lo;
            }
          }
        }
        Treg = unmono((unsigned)(kq[KNN-1] >> 32));
      }
    }
    __syncthreads();
  }

  if (lane < 16){
    int* o = idxout + ((size_t)b*N_ + i0 + w*16 + lane)*KNN;
#pragma unroll
    for (int q=0;q<KNN;q++) o[q] = (int)(4095u - (unsigned)((kq[q]>>4) & 4095ull));
  }
}

// ---------------- generic GEMM: Y(M x Pfull) = act(s*(X1@Wa + X2@Wb)+b) ----------
template<int PT>
__global__ __launch_bounds__(256) void k_gemm(
    const float* __restrict__ X1, int C1,
    const float* __restrict__ X2, int C2,
    const float* __restrict__ W, int hmask, int hshift, int wstride, int hoff,
    const float* __restrict__ g, const float* __restrict__ bb, int act,
    float* __restrict__ Y, int Pfull)
{
  constexpr int CPT = PT/16;
  constexpr int WLS = PT + 4;
  __shared__ float Xt[32*68];
  __shared__ float Wt[32*WLS];
  const int t  = threadIdx.x;
  const int r0 = blockIdx.x*64;
  const int p0 = blockIdx.y*PT;
  const int cg = t & 15, rg = t >> 4;
  const int C = C1 + C2;
  const int nkt = (C + 31) >> 5;

  float acc[4][CPT];
#pragma unroll
  for (int a=0;a<4;a++)
#pragma unroll
    for (int c=0;c<CPT;c++) acc[a][c]=0.f;

  for (int kt = 0; kt < nkt; ++kt){
    const int k0 = kt*32;
#pragma unroll
    for (int e = t; e < 64*32; e += 256){
      int kk = e & 31, r = e >> 5;
      int gk = k0 + kk;
      float v = 0.f;
      if (gk < C1) v = X1[(size_t)(r0+r)*C1 + gk];
      else if (gk < C) v = X2[(size_t)(r0+r)*C2 + (gk - C1)];
      Xt[kk*68 + r] = v;
    }
#pragma unroll
    for (int e = t; e < PT*32; e += 256){
      int kk = e & 31, p = e >> 5;
      int gp = p0 + p;
      int wrow = (gp & hmask)*wstride + (gp >> hshift)*hoff;
      int gk = k0 + kk;
      Wt[kk*WLS + p] = (gk < C) ? W[(size_t)wrow + gk] : 0.f;
    }
    __syncthreads();
#pragma unroll
    for (int kk=0;kk<32;kk++){
      float4 xv = *(const float4*)&Xt[kk*68 + rg*4];
      float xr[4] = {xv.x, xv.y, xv.z, xv.w};
      float wv[CPT];
#pragma unroll
      for (int c4=0;c4<CPT/4;c4++){
        float4 w4 = *(const float4*)&Wt[kk*WLS + cg*CPT + c4*4];
        wv[c4*4+0]=w4.x; wv[c4*4+1]=w4.y; wv[c4*4+2]=w4.z; wv[c4*4+3]=w4.w;
      }
#pragma unroll
      for (int rr=0;rr<4;rr++)
#pragma unroll
        for (int cc=0;cc<CPT;cc++)
          acc[rr][cc] = fmaf(xr[rr], wv[cc], acc[rr][cc]);
    }
    __syncthreads();
  }

  const float srs = rsqrtf(1.f + 1e-5f);
  float sv[CPT], bvv[CPT];
#pragma unroll
  for (int cc=0;cc<CPT;cc++){
    int gp = p0 + cg*CPT + cc;
    if (g){ sv[cc] = g[gp]*srs; bvv[cc] = bb[gp]; } else { sv[cc]=1.f; bvv[cc]=0.f; }
  }
#pragma unroll
  for (int rr=0;rr<4;rr++){
    size_t row = r0 + rg*4 + rr;
    float* yr = Y + row*(size_t)Pfull + p0 + cg*CPT;
#pragma unroll
    for (int c4=0;c4<CPT/4;c4++){
      float y0 = sv[c4*4+0]*acc[rr][c4*4+0] + bvv[c4*4+0];
      float y1 = sv[c4*4+1]*acc[rr][c4*4+1] + bvv[c4*4+1];
      float y2 = sv[c4*4+2]*acc[rr][c4*4+2] + bvv[c4*4+2];
      float y3 = sv[c4*4+3]*acc[rr][c4*4+3] + bvv[c4*4+3];
      if (act){ y0=mishf(y0); y1=mishf(y1); y2=mishf(y2); y3=mishf(y3); }
      *(float4*)&yr[c4*4] = make_float4(y0,y1,y2,y3);
    }
  }
}

// ---------------- edge gather + BN + mish + max over k ----------------
template<int O>
__global__ __launch_bounds__(256) void k_edgemax(
    const float* __restrict__ ua, const int* __restrict__ idx,
    const float* __restrict__ g, const float* __restrict__ bb,
    float* __restrict__ Y)
{
  constexpr int TPR = O/4;
  const int gt = blockIdx.x*256 + threadIdx.x;
  const int m  = gt / TPR;
  const int og = gt % TPR;
  if (m >= M_) return;
  const int base = m & ~(N_-1);
  const int P = 2*O;
  const float4 u0 = *(const float4*)&ua[(size_t)m*P + og*4];
  const float4 a0 = *(const float4*)&ua[(size_t)m*P + O + og*4];
  const float srs = rsqrtf(1.f + 1e-5f);
  const float4 gv  = *(const float4*)&g[og*4];
  const float4 bv4 = *(const float4*)&bb[og*4];
  const float sx = gv.x*srs, sy = gv.y*srs, sz = gv.z*srs, sw = gv.w*srs;
  const float cx = a0.x - u0.x, cy = a0.y - u0.y, cz = a0.z - u0.z, cw = a0.w - u0.w;
  float mx = -INFINITY, my = -INFINITY, mz = -INFINITY, mw = -INFINITY;
  const int* id = idx + (size_t)m*KNN;
#pragma unroll
  for (int k=0;k<KNN;k++){
    int j = id[k];
    const float4 uj = *(const float4*)&ua[(size_t)(base + j)*P + og*4];
    float zx = fmaf(sx, uj.x + cx, bv4.x);
    float zy = fmaf(sy, uj.y + cy, bv4.y);
    float zz = fmaf(sz, uj.z + cz, bv4.z);
    float zw = fmaf(sw, uj.w + cw, bv4.w);
    mx = fmaxf(mx, mishf(zx));
    my = fmaxf(my, mishf(zy));
    mz = fmaxf(mz, mishf(zz));
    mw = fmaxf(mw, mishf(zw));
  }
  *(float4*)&Y[(size_t)m*O + og*4] = make_float4(mx,my,mz,mw);
}

// ---------------- final projection: out(B,2,N) = W9 @ h8 ----------------
__global__ __launch_bounds__(256) void k_final(const float* __restrict__ h,
                                               const float* __restrict__ W9,
                                               float* __restrict__ out){
  __shared__ float w[128];
  const int t = threadIdx.x;
  if (t < 128) w[t] = W9[t];
  __syncthreads();
  const int m = blockIdx.x*256 + t;
  if (m >= M_) return;
  const int b = m >> 12, i = m & (N_-1);
  const float* hr = h + (size_t)m*64;
  float s0 = 0.f, s1 = 0.f;
#pragma unroll
  for (int c=0;c<64;c++){ float v = hr[c]; s0 = fmaf(w[c], v, s0); s1 = fmaf(w[64+c], v, s1); }
  out[((size_t)b*2 + 0)*N_ + i] = s0;
  out[((size_t)b*2 + 1)*N_ + i] = s1;
}

extern "C" void kernel_launch(void* const* d_in, const int* in_sizes, int n_in,
                              void* d_out, int out_size, void* d_ws, size_t ws_size,
                              hipStream_t stream)
{
  const float* x  = (const float*)d_in[0];
  const float* W1 = (const float*)d_in[1];
  const float* W2 = (const float*)d_in[2];
  const float* W3 = (const float*)d_in[3];
  const float* W4 = (const float*)d_in[4];
  const float* W5 = (const float*)d_in[5];
  const float* W6 = (const float*)d_in[6];
  const float* W7 = (const float*)d_in[7];
  const float* W8 = (const float*)d_in[8];
  const float* W9 = (const float*)d_in[9];
  const float* g1 = (const float*)d_in[10]; const float* b1 = (const float*)d_in[11];
  const float* g2 = (const float*)d_in[12]; const float* b2 = (const float*)d_in[13];
  const float* g3 = (const float*)d_in[14]; const float* b3 = (const float*)d_in[15];
  const float* g4 = (const float*)d_in[16]; const float* b4 = (const float*)d_in[17];
  const float* g5 = (const float*)d_in[18]; const float* b5 = (const float*)d_in[19];
  const float* g6 = (const float*)d_in[20]; const float* b6 = (const float*)d_in[21];
  const float* g7 = (const float*)d_in[22]; const float* b7 = (const float*)d_in[23];
  const float* g8 = (const float*)d_in[24]; const float* b8 = (const float*)d_in[25];
  float* out = (float*)d_out;

  float* ws  = (float*)d_ws;
  float* xp  = ws;                       // 98304
  float* xx  = xp + 98304;               // 32768
  int*   idx = (int*)(xx + 32768);       // 327680 ints
  float* ua  = (float*)(idx + 327680);   // 8388608 floats (max M*256)
  float* x1  = ua + 8388608;             // M*64
  float* x2  = x1 + 2097152;             // M*64
  float* x3  = x2 + 2097152;             // M*128
  float* h4  = x3 + 4194304;             // M*128
  float* h5  = h4 + 4194304;             // M*128
  float* h6  = x3;
  float* h7  = h4;
  float* h8  = h5;
  // bf16 split buffers alias the (currently dead) ua region during kNN
  ushort* Xhi = (ushort*)ua;             // M*64 ushorts = 1M floats
  ushort* Xlo = (ushort*)(ua + 1048576); // M*64 ushorts

  const dim3 blk(256);
  const float* nullf = nullptr;

  // ---- stage 1 (C=3 -> 64) ----
  k_transpose_x<<<dim3(M_/256), blk, 0, stream>>>(x, xp);
  k_xx<3><<<dim3(M_/256), blk, 0, stream>>>(xp, xx);
  k_knn<3><<<dim3(N_/64, B_), blk, 0, stream>>>(xp, xx, idx);
  k_gemm<128><<<dim3(M_/64, 1), blk, 0, stream>>>(xp, 3, nullf, 0,
      W1, 63, 6, 6, 3, nullf, nullf, 0, ua, 128);
  k_edgemax<64><<<dim3(M_*16/256), blk, 0, stream>>>(ua, idx, g1, b1, x1);

  // ---- stage 2 (64 -> 64) ----
  k_xx<64><<<dim3(M_/256), blk, 0, stream>>>(x1, xx);
  k_cvt<<<dim3(M_*64/(8*256)), blk, 0, stream>>>(x1, Xhi, Xlo);
  k_knn64m<<<dim3(512), blk, 0, stream>>>(Xhi, Xlo, xx, idx);
  k_gemm<128><<<dim3(M_/64, 1), blk, 0, stream>>>(x1, 64, nullf, 0,
      W2, 63, 6, 128, 64, nullf, nullf, 0, ua, 128);
  k_edgemax<64><<<dim3(M_*16/256), blk, 0, stream>>>(ua, idx, g2, b2, x2);

  // ---- stage 3 (64 -> 128) ----
  k_xx<64><<<dim3(M_/256), blk, 0, stream>>>(x2, xx);
  k_cvt<<<dim3(M_*64/(8*256)), blk, 0, stream>>>(x2, Xhi, Xlo);
  k_knn64m<<<dim3(512), blk, 0, stream>>>(Xhi, Xlo, xx, idx);
  k_gemm<128><<<dim3(M_/64, 2), blk, 0, stream>>>(x2, 64, nullf, 0,
      W3, 127, 7, 128, 64, nullf, nullf, 0, ua, 256);
  k_edgemax<128><<<dim3(M_*32/256), blk, 0, stream>>>(ua, idx, g3, b3, x3);

  // ---- MLP head ----
  k_gemm<128><<<dim3(M_/64, 1), blk, 0, stream>>>(x3, 128, nullf, 0,
      W4, 127, 7, 128, 0, g4, b4, 1, h4, 128);
  k_gemm<128><<<dim3(M_/64, 1), blk, 0, stream>>>(h4, 128, x3, 128,
      W5, 127, 7, 256, 0, g5, b5, 1, h5, 128);
  k_gemm<64><<<dim3(M_/64, 1), blk, 0, stream>>>(h5, 128, nullf, 0,
      W6, 63, 6, 128, 0, g6, b6, 1, h6, 64);
  k_gemm<64><<<dim3(M_/64, 1), blk, 0, stream>>>(h6, 64, x2, 64,
      W7, 63, 6, 128, 0, g7, b7, 1, h7, 64);
  k_gemm<64><<<dim3(M_/64, 1), blk, 0, stream>>>(h7, 64, x1, 64,
      W8, 63, 6, 128, 0, g8, b8, 1, h8, 64);
  k_final<<<dim3(M_/256), blk, 0, stream>>>(h8, W9, out);
}

// Round 11
// 1489.023 us; speedup vs baseline: 1.4846x; 1.0860x over previous
//
#include <hip/hip_runtime.h>
#include <hip/hip_bf16.h>
#include <math.h>
#include <float.h>

#define B_ 8
#define N_ 4096
#define M_ (B_*N_)
#define KNN 10

typedef unsigned long long ull;
typedef __attribute__((ext_vector_type(8))) short s16x8;
typedef __attribute__((ext_vector_type(4))) float f32x4;

__device__ __forceinline__ float mishf(float x){
  float sp = (x > 20.f) ? x : __logf(1.f + __expf(x));
  float e2 = __expf(-2.f*sp);
  float th = (1.f - e2) / (1.f + e2);
  return x * th;
}

__device__ __forceinline__ ull shfl_xor_u64(ull v, int mask){
  unsigned lo = (unsigned)v, hi = (unsigned)(v >> 32);
  lo = (unsigned)__shfl_xor((int)lo, mask);
  hi = (unsigned)__shfl_xor((int)hi, mask);
  return ((ull)hi << 32) | lo;
}
__device__ __forceinline__ ull shfl_u64(ull v, int src){
  unsigned lo = (unsigned)v, hi = (unsigned)(v >> 32);
  lo = (unsigned)__shfl((int)lo, src);
  hi = (unsigned)__shfl((int)hi, src);
  return ((ull)hi << 32) | lo;
}
__device__ __forceinline__ int mbcnt_lt(ull mask){
  return __builtin_amdgcn_mbcnt_hi((unsigned)(mask>>32),
         __builtin_amdgcn_mbcnt_lo((unsigned)mask, 0));
}
__device__ __forceinline__ unsigned mono_u32(float f){
  unsigned u = __float_as_uint(f);
  return u ^ ((unsigned)((int)u >> 31) | 0x80000000u);
}
__device__ __forceinline__ float unmono(unsigned vk){
  unsigned u = (vk & 0x80000000u) ? (vk ^ 0x80000000u) : ~vk;
  return __uint_as_float(u);
}
// async global->LDS, 16B per lane; lds dest is wave-uniform base + lane*16
__device__ __forceinline__ void gload_lds16(const void* g, void* l){
  __builtin_amdgcn_global_load_lds(
      (const __attribute__((address_space(1))) unsigned int*)g,
      (__attribute__((address_space(3))) unsigned int*)l, 16, 0, 0);
}

// ---------------- transpose x (B,3,N) -> xp (B*N,3) ----------------
__global__ __launch_bounds__(256) void k_transpose_x(const float* __restrict__ x,
                                                     float* __restrict__ xp){
  int n = blockIdx.x*256 + threadIdx.x;
  if (n >= M_) return;
  int b = n >> 12, i = n & (N_-1);
  const float* xb = x + (size_t)b*3*N_;
  float v0 = xb[i], v1 = xb[N_+i], v2 = xb[2*N_+i];
  float* o = xp + (size_t)n*3;
  o[0]=v0; o[1]=v1; o[2]=v2;
}

// ---------------- xx[n] = sum_c X[n,c]^2 ----------------
template<int C>
__global__ __launch_bounds__(256) void k_xx(const float* __restrict__ X,
                                            float* __restrict__ xx){
  int n = blockIdx.x*256 + threadIdx.x;
  if (n >= M_) return;
  const float* r = X + (size_t)n*C;
  float s = 0.f;
#pragma unroll
  for (int c=0;c<C;c++){ float v=r[c]; s = fmaf(v,v,s); }
  xx[n] = s;
}

// ---------------- split fp32 -> bf16 hi + bf16 lo (exact 2-term split) ------
__global__ __launch_bounds__(256) void k_cvt(const float* __restrict__ X,
                                             ushort* __restrict__ Xhi,
                                             ushort* __restrict__ Xlo){
  int i = blockIdx.x*256 + threadIdx.x;
  const float4* src = (const float4*)X + (size_t)i*2;
  float4 v0 = src[0], v1 = src[1];
  float vv[8] = {v0.x,v0.y,v0.z,v0.w,v1.x,v1.y,v1.z,v1.w};
  ushort h[8], l[8];
#pragma unroll
  for (int e=0;e<8;e++){
    __hip_bfloat16 hb = __float2bfloat16(vv[e]);
    float hf = __bfloat162float(hb);
    __hip_bfloat16 lb = __float2bfloat16(vv[e]-hf);
    h[e] = *(ushort*)&hb; l[e] = *(ushort*)&lb;
  }
  uint4 hp, lp;
  hp.x = (unsigned)h[0] | ((unsigned)h[1]<<16);
  hp.y = (unsigned)h[2] | ((unsigned)h[3]<<16);
  hp.z = (unsigned)h[4] | ((unsigned)h[5]<<16);
  hp.w = (unsigned)h[6] | ((unsigned)h[7]<<16);
  lp.x = (unsigned)l[0] | ((unsigned)l[1]<<16);
  lp.y = (unsigned)l[2] | ((unsigned)l[3]<<16);
  lp.z = (unsigned)l[4] | ((unsigned)l[5]<<16);
  lp.w = (unsigned)l[6] | ((unsigned)l[7]<<16);
  *(uint4*)(Xhi + (size_t)i*8) = hp;
  *(uint4*)(Xlo + (size_t)i*8) = lp;
}

// ---------------- MFMA kNN (C=64, split-bf16 exact gram) ----------------
// R7 config (grid 512, full j-scan, (256,2)) + LDS double-buffer with
// ASYNC global_load_lds staging (R10's reg-staging spilled to scratch: 176MB
// WRITE_SIZE). Swizzle handled per rule #21: LDS write is LINEAR (HW), the
// per-lane GLOBAL source address carries the inverse XOR permutation
// (chunk sc = c ^ lr), and reads re-apply the same XOR -> src[r][k] exact.
// One barrier/tile; prefetch drains at the barrier ~2000cyc after issue.
__global__ __launch_bounds__(256,2) void k_knn64m(const ushort* __restrict__ Xhi,
                                                  const ushort* __restrict__ Xlo,
                                                  const float* __restrict__ xx,
                                                  int* __restrict__ idxout){
  constexpr int JT  = 128;
  constexpr int NT  = N_/JT;
  constexpr int CAP = 320;
  __shared__ ushort XJhi[2][JT*64];   // content: LDS[r][c] = src[r][c ^ (r&7)] (16B chunks)
  __shared__ ushort XJlo[2][JT*64];
  __shared__ float  halfxx[2][JT];
  __shared__ ull    buf[4][CAP];

  const int t    = threadIdx.x;
  const int w    = t >> 6;
  const int lane = t & 63;
  const int b    = blockIdx.x & 7;          // XCD-swizzle: batch per XCD
  const int i0   = (blockIdx.x >> 3) * 64;
  const size_t rowbase = (size_t)b*N_;
  const float* xxb = xx + rowbase;

  // ---- A fragments (this wave's 16 rows) ----
  const int arow = i0 + w*16 + (lane & 15);
  const ushort* Ah = Xhi + (rowbase + arow)*64;
  const ushort* Al = Xlo + (rowbase + arow)*64;
  const int ko = (lane >> 4)*8;
  s16x8 aH0 = *(const s16x8*)(Ah + ko);
  s16x8 aH1 = *(const s16x8*)(Ah + 32 + ko);
  s16x8 aL0 = *(const s16x8*)(Al + ko);
  s16x8 aL1 = *(const s16x8*)(Al + 32 + ko);

  ull kq[KNN];
#pragma unroll
  for (int q=0;q<KNN;q++) kq[q]=0ull;
  float Treg = -INFINITY;

  // per-lane source chunk permutation for linear-LDS async staging
  const int lr = lane >> 3;          // row within 8-row segment
  const int sc = (lane & 7) ^ lr;    // pre-swizzled source chunk

  // prologue: stage tile 0 into buffer 0
  {
#pragma unroll
    for (int seg=0; seg<4; ++seg){
      const int row0 = w*32 + seg*8;
      gload_lds16(Xhi + (rowbase + row0 + lr)*64 + sc*8, &XJhi[0][row0*64]);
      gload_lds16(Xlo + (rowbase + row0 + lr)*64 + sc*8, &XJlo[0][row0*64]);
    }
    if (t < JT) halfxx[0][t] = 0.5f*xxb[t];
  }
  __syncthreads();

  for (int jt = 0; jt < NT; ++jt){
    const int cur = jt & 1;
    const int j0 = jt*JT;

    // ---- async-prefetch tile jt+1 into buffer cur^1 ----
    float hnext = 0.f;
    if (jt < NT-1){
      const size_t nb0 = rowbase + j0 + JT;
#pragma unroll
      for (int seg=0; seg<4; ++seg){
        const int row0 = w*32 + seg*8;
        gload_lds16(Xhi + (nb0 + row0 + lr)*64 + sc*8, &XJhi[cur^1][row0*64]);
        gload_lds16(Xlo + (nb0 + row0 + lr)*64 + sc*8, &XJlo[cur^1][row0*64]);
      }
      if (t < JT) hnext = 0.5f*xxb[j0 + JT + t];
    }

    // ---- gram: 8 col-blocks x (2 khalf x 4 products) MFMA on buffer cur ----
    f32x4 acc[8];
#pragma unroll
    for (int cb=0;cb<8;cb++) acc[cb] = (f32x4){0.f,0.f,0.f,0.f};

#pragma unroll
    for (int cb=0;cb<8;cb++){
      const int brow = cb*16 + (lane & 15);
      const unsigned sw = ((unsigned)(brow & 7)) << 4;
      const char* ph = (const char*)&XJhi[cur][0] + brow*128;
      const char* pl = (const char*)&XJlo[cur][0] + brow*128;
      const int kb0 = (int)((unsigned)((lane>>4)<<4) ^ sw);
      const int kb1 = (int)((unsigned)(64 | ((lane>>4)<<4)) ^ sw);
      s16x8 bh0 = *(const s16x8*)(ph + kb0);
      s16x8 bl0 = *(const s16x8*)(pl + kb0);
      s16x8 bh1 = *(const s16x8*)(ph + kb1);
      s16x8 bl1 = *(const s16x8*)(pl + kb1);
      f32x4 a = acc[cb];
      a = __builtin_amdgcn_mfma_f32_16x16x32_bf16(aH0, bh0, a, 0,0,0);
      a = __builtin_amdgcn_mfma_f32_16x16x32_bf16(aH0, bl0, a, 0,0,0);
      a = __builtin_amdgcn_mfma_f32_16x16x32_bf16(aL0, bh0, a, 0,0,0);
      a = __builtin_amdgcn_mfma_f32_16x16x32_bf16(aL0, bl0, a, 0,0,0);
      a = __builtin_amdgcn_mfma_f32_16x16x32_bf16(aH1, bh1, a, 0,0,0);
      a = __builtin_amdgcn_mfma_f32_16x16x32_bf16(aH1, bl1, a, 0,0,0);
      a = __builtin_amdgcn_mfma_f32_16x16x32_bf16(aL1, bh1, a, 0,0,0);
      a = __builtin_amdgcn_mfma_f32_16x16x32_bf16(aL1, bl1, a, 0,0,0);
      acc[cb] = a;
    }

    float hx[8];
#pragma unroll
    for (int cb=0;cb<8;cb++) hx[cb] = halfxx[cur][cb*16 + (lane & 15)];

    // ---- write prefetched halfxx (load issued before gram; hidden) ----
    if (jt < NT-1 && t < JT) halfxx[cur^1][t] = hnext;

    if (jt == 0){
      // ---- bootstrap: exact top-10 of first 128 cols per row ----
#pragma unroll
      for (int reg=0;reg<4;reg++){
        const unsigned rl = (unsigned)((lane>>4)*4 + reg);
        ull k8[8];
#pragma unroll
        for (int cb=0;cb<8;cb++){
          float v = acc[cb][reg] - hx[cb];
          unsigned jinv = 4095u - (unsigned)(cb*16 + (lane & 15));
          k8[cb] = ((ull)mono_u32(v)<<32) | ((ull)jinv<<4) | rl;
        }
#pragma unroll
        for (int q=0;q<KNN;q++){
          ull m = k8[0];
#pragma unroll
          for (int s=1;s<8;s++) m = m > k8[s] ? m : k8[s];
          ull v1 = shfl_xor_u64(m,1); m = m>v1?m:v1;
          ull v2 = shfl_xor_u64(m,2); m = m>v2?m:v2;
          ull v4 = shfl_xor_u64(m,4); m = m>v4?m:v4;
          ull v8 = shfl_xor_u64(m,8); m = m>v8?m:v8;
          ull mv = shfl_u64(m, (lane>>2)<<4);
          if (lane < 16 && (lane&3)==reg) kq[q] = mv;
#pragma unroll
          for (int s=0;s<8;s++) k8[s] = (k8[s]==m) ? 0ull : k8[s];
        }
      }
      Treg = unmono((unsigned)(kq[KNN-1] >> 32));
    } else {
      // ---- filter & compact survivors ----
      float Tf[4];
#pragma unroll
      for (int reg=0;reg<4;reg++) Tf[reg] = __shfl(Treg, (lane>>4)*4 + reg);
      int cnt = 0;
#pragma unroll
      for (int cb=0;cb<8;cb++){
#pragma unroll
        for (int reg=0;reg<4;reg++){
          float v = acc[cb][reg] - hx[cb];
          bool pass = v >= Tf[reg];
          ull mask = __ballot(pass);
          if (mask){
            if (pass){
              int slot = cnt + mbcnt_lt(mask);
              unsigned jinv = 4095u - (unsigned)(j0 + cb*16 + (lane & 15));
              ull key = ((ull)mono_u32(v)<<32) | ((ull)jinv<<4)
                        | (unsigned)((lane>>4)*4 + reg);
              if (slot < CAP) buf[w][slot] = key;
            }
            cnt += __popcll(mask);
          }
        }
      }
      // ---- drain (chunks of 4: overlap ds_read latency; 0-pad never inserts) ----
      if (cnt){
        int nb = cnt < CAP ? cnt : CAP;
        int pad = (4 - (nb & 3)) & 3;
        if (lane < pad && nb + lane < CAP) buf[w][nb + lane] = 0ull;
        int nb4 = nb + pad; if (nb4 > CAP) nb4 = CAP;
        for (int e=0;e<nb4;e+=4){
          ull c0=buf[w][e+0], c1=buf[w][e+1], c2=buf[w][e+2], c3=buf[w][e+3];
#pragma unroll
          for (int u=0;u<4;u++){
            ull k64 = (u==0)?c0:(u==1)?c1:(u==2)?c2:c3;
            if ((int)(k64 & 15ull) == lane && k64 > kq[KNN-1]){
              ull ck = k64;
#pragma unroll
              for (int q=0;q<KNN;q++){
                ull hi = ck > kq[q] ? ck : kq[q];
                ull lo = ck > kq[q] ? kq[q] : ck;
                kq[q] = hi; ck = lo;
              }
            }
          }
        }
        Treg = unmono((unsigned)(kq[KNN-1] >> 32));
      }
    }
    __syncthreads();   // drains prefetch (vmcnt) + protects buffer swap
  }

  if (lane < 16){
    int* o = idxout + ((size_t)b*N_ + i0 + w*16 + lane)*KNN;
#pragma unroll
    for (int q=0;q<KNN;q++) o[q] = (int)(4095u - (unsigned)((kq[q]>>4) & 4095ull));
  }
}

// ---------------- fp32 kNN (kept for C=3 stage) -- R7 config ----------------
template<int C>
__global__ __launch_bounds__(256,2) void k_knn(const float* __restrict__ X,
                                               const float* __restrict__ xx,
                                               int* __restrict__ idxout){
  constexpr bool BIG = (C % 4 == 0);
  constexpr int LS  = BIG ? (C + 4) : 12;
  constexpr int NC4 = BIG ? (C/4 + 1) : 1;
  constexpr int JT  = 128;
  constexpr int CAP = 320;
  __shared__ float XI[64*LS];
  __shared__ float XJ[JT*LS];
  __shared__ ull   buf[4][CAP];

  const int t    = threadIdx.x;
  const int w    = t >> 6;
  const int lane = t & 63;
  const int b    = blockIdx.y;
  const int i0   = blockIdx.x*64;
  const int tc   = t & 15, tr = t >> 4;
  const float* Xb  = X  + (size_t)b*N_*C;
  const float* xxb = xx + (size_t)b*N_;

  if constexpr (BIG){
    for (int f = t; f < 64*(C/4); f += 256){
      int r = f >> 4, c4 = f & 15;
      *(float4*)&XI[r*LS + c4*4] = *(const float4*)&Xb[(size_t)(i0+r)*C + c4*4];
    }
    if (t < 64){ XI[t*LS+C]=1.f; XI[t*LS+C+1]=0.f; XI[t*LS+C+2]=0.f; XI[t*LS+C+3]=0.f; }
  } else {
    if (t < 64){
      const float* p = &Xb[(size_t)(i0+t)*C];
      XI[t*LS+0]=p[0]; XI[t*LS+1]=p[1]; XI[t*LS+2]=p[2]; XI[t*LS+3]=1.f;
    }
  }

  ull kq[KNN];
#pragma unroll
  for (int q=0;q<KNN;q++) kq[q]=0ull;
  float Treg = -INFINITY;

  for (int jt = 0; jt < N_/JT; ++jt){
    const int j0 = jt*JT;
    if constexpr (BIG){
      for (int f = t; f < JT*(C/4); f += 256){
        int r = f >> 4, c4 = f & 15;
        *(float4*)&XJ[r*LS + c4*4] = *(const float4*)&Xb[(size_t)(j0+r)*C + c4*4];
      }
      if (t < JT){ XJ[t*LS+C] = -0.5f*xxb[j0+t]; XJ[t*LS+C+1]=0.f; XJ[t*LS+C+2]=0.f; XJ[t*LS+C+3]=0.f; }
    } else {
      if (t < JT){
        const float* p = &Xb[(size_t)(j0+t)*C];
        XJ[t*LS+0]=p[0]; XJ[t*LS+1]=p[1]; XJ[t*LS+2]=p[2]; XJ[t*LS+3]=-0.5f*xxb[j0+t];
      }
    }
    __syncthreads();

    float acc[4][8];
#pragma unroll
    for (int rr=0;rr<4;rr++)
#pragma unroll
      for (int s=0;s<8;s++) acc[rr][s]=0.f;

#pragma unroll 2
    for (int c4 = 0; c4 < NC4; ++c4){
      float4 xi0 = *(const float4*)&XI[(tr*4+0)*LS + c4*4];
      float4 xi1 = *(const float4*)&XI[(tr*4+1)*LS + c4*4];
      float4 xi2 = *(const float4*)&XI[(tr*4+2)*LS + c4*4];
      float4 xi3 = *(const float4*)&XI[(tr*4+3)*LS + c4*4];
#pragma unroll
      for (int s=0;s<8;s++){
        float4 xj = *(const float4*)&XJ[(tc+16*s)*LS + c4*4];
        float a0=acc[0][s], a1=acc[1][s], a2=acc[2][s], a3=acc[3][s];
        a0=fmaf(xi0.x,xj.x,a0); a1=fmaf(xi1.x,xj.x,a1); a2=fmaf(xi2.x,xj.x,a2); a3=fmaf(xi3.x,xj.x,a3);
        a0=fmaf(xi0.y,xj.y,a0); a1=fmaf(xi1.y,xj.y,a1); a2=fmaf(xi2.y,xj.y,a2); a3=fmaf(xi3.y,xj.y,a3);
        a0=fmaf(xi0.z,xj.z,a0); a1=fmaf(xi1.z,xj.z,a1); a2=fmaf(xi2.z,xj.z,a2); a3=fmaf(xi3.z,xj.z,a3);
        a0=fmaf(xi0.w,xj.w,a0); a1=fmaf(xi1.w,xj.w,a1); a2=fmaf(xi2.w,xj.w,a2); a3=fmaf(xi3.w,xj.w,a3);
        acc[0][s]=a0; acc[1][s]=a1; acc[2][s]=a2; acc[3][s]=a3;
      }
    }

    if (jt == 0){
#pragma unroll
      for (int rr=0;rr<4;rr++){
        const unsigned rl = (unsigned)((lane>>4)*4 + rr);
        ull k8[8];
#pragma unroll
        for (int s=0;s<8;s++){
          unsigned jinv = 4095u - (unsigned)(tc + 16*s);
          k8[s] = ((ull)mono_u32(acc[rr][s])<<32) | ((ull)jinv<<4) | rl;
        }
#pragma unroll
        for (int q=0;q<KNN;q++){
          ull m = k8[0];
#pragma unroll
          for (int s=1;s<8;s++) m = m > k8[s] ? m : k8[s];
          ull v1 = shfl_xor_u64(m,1); m = m>v1?m:v1;
          ull v2 = shfl_xor_u64(m,2); m = m>v2?m:v2;
          ull v4 = shfl_xor_u64(m,4); m = m>v4?m:v4;
          ull v8 = shfl_xor_u64(m,8); m = m>v8?m:v8;
          ull mv = shfl_u64(m, (lane>>2)<<4);
          if (lane < 16 && (lane&3)==rr) kq[q] = mv;
#pragma unroll
          for (int s=0;s<8;s++) k8[s] = (k8[s]==m) ? 0ull : k8[s];
        }
      }
      Treg = unmono((unsigned)(kq[KNN-1] >> 32));
    } else {
      float Tf[4];
#pragma unroll
      for (int rr=0;rr<4;rr++) Tf[rr] = __shfl(Treg, (lane>>4)*4 + rr);
      int cnt = 0;
#pragma unroll
      for (int s=0;s<8;s++){
#pragma unroll
        for (int rr=0;rr<4;rr++){
          bool pass = acc[rr][s] >= Tf[rr];
          ull mask = __ballot(pass);
          if (mask){
            if (pass){
              int slot = cnt + mbcnt_lt(mask);
              unsigned jinv = 4095u - (unsigned)(j0 + tc + 16*s);
              ull key = ((ull)mono_u32(acc[rr][s])<<32) | ((ull)jinv<<4)
                        | (unsigned)((lane>>4)*4 + rr);
              if (slot < CAP) buf[w][slot] = key;
            }
            cnt += __popcll(mask);
          }
        }
      }
      if (cnt){
        int nb = cnt < CAP ? cnt : CAP;
        for (int e=0;e<nb;e++){
          ull k64 = buf[w][e];
          if ((int)(k64 & 15ull) == lane && k64 > kq[KNN-1]){
            ull ck = k64;
#pragma unroll
            for (int q=0;q<KNN;q++){
              ull hi = ck > kq[q] ? ck : kq[q];
              ull lo = ck > kq[q] ? kq[q] : ck;
              kq[q] = hi; ck = lo;
            }
          }
        }
        Treg = unmono((unsigned)(kq[KNN-1] >> 32));
      }
    }
    __syncthreads();
  }

  if (lane < 16){
    int* o = idxout + ((size_t)b*N_ + i0 + w*16 + lane)*KNN;
#pragma unroll
    for (int q=0;q<KNN;q++) o[q] = (int)(4095u - (unsigned)((kq[q]>>4) & 4095ull));
  }
}

// ---------------- generic GEMM: Y(M x Pfull) = act(s*(X1@Wa + X2@Wb)+b) ----------
template<int PT>
__global__ __launch_bounds__(256) void k_gemm(
    const float* __restrict__ X1, int C1,
    const float* __restrict__ X2, int C2,
    const float* __restrict__ W, int hmask, int hshift, int wstride, int hoff,
    const float* __restrict__ g, const float* __restrict__ bb, int act,
    float* __restrict__ Y, int Pfull)
{
  constexpr int CPT = PT/16;
  constexpr int WLS = PT + 4;
  __shared__ float Xt[32*68];
  __shared__ float Wt[32*WLS];
  const int t  = threadIdx.x;
  const int r0 = blockIdx.x*64;
  const int p0 = blockIdx.y*PT;
  const int cg = t & 15, rg = t >> 4;
  const int C = C1 + C2;
  const int nkt = (C + 31) >> 5;

  float acc[4][CPT];
#pragma unroll
  for (int a=0;a<4;a++)
#pragma unroll
    for (int c=0;c<CPT;c++) acc[a][c]=0.f;

  for (int kt = 0; kt < nkt; ++kt){
    const int k0 = kt*32;
#pragma unroll
    for (int e = t; e < 64*32; e += 256){
      int kk = e & 31, r = e >> 5;
      int gk = k0 + kk;
      float v = 0.f;
      if (gk < C1) v = X1[(size_t)(r0+r)*C1 + gk];
      else if (gk < C) v = X2[(size_t)(r0+r)*C2 + (gk - C1)];
      Xt[kk*68 + r] = v;
    }
#pragma unroll
    for (int e = t; e < PT*32; e += 256){
      int kk = e & 31, p = e >> 5;
      int gp = p0 + p;
      int wrow = (gp & hmask)*wstride + (gp >> hshift)*hoff;
      int gk = k0 + kk;
      Wt[kk*WLS + p] = (gk < C) ? W[(size_t)wrow + gk] : 0.f;
    }
    __syncthreads();
#pragma unroll
    for (int kk=0;kk<32;kk++){
      float4 xv = *(const float4*)&Xt[kk*68 + rg*4];
      float xr[4] = {xv.x, xv.y, xv.z, xv.w};
      float wv[CPT];
#pragma unroll
      for (int c4=0;c4<CPT/4;c4++){
        float4 w4 = *(const float4*)&Wt[kk*WLS + cg*CPT + c4*4];
        wv[c4*4+0]=w4.x; wv[c4*4+1]=w4.y; wv[c4*4+2]=w4.z; wv[c4*4+3]=w4.w;
      }
#pragma unroll
      for (int rr=0;rr<4;rr++)
#pragma unroll
        for (int cc=0;cc<CPT;cc++)
          acc[rr][cc] = fmaf(xr[rr], wv[cc], acc[rr][cc]);
    }
    __syncthreads();
  }

  const float srs = rsqrtf(1.f + 1e-5f);
  float sv[CPT], bvv[CPT];
#pragma unroll
  for (int cc=0;cc<CPT;cc++){
    int gp = p0 + cg*CPT + cc;
    if (g){ sv[cc] = g[gp]*srs; bvv[cc] = bb[gp]; } else { sv[cc]=1.f; bvv[cc]=0.f; }
  }
#pragma unroll
  for (int rr=0;rr<4;rr++){
    size_t row = r0 + rg*4 + rr;
    float* yr = Y + row*(size_t)Pfull + p0 + cg*CPT;
#pragma unroll
    for (int c4=0;c4<CPT/4;c4++){
      float y0 = sv[c4*4+0]*acc[rr][c4*4+0] + bvv[c4*4+0];
      float y1 = sv[c4*4+1]*acc[rr][c4*4+1] + bvv[c4*4+1];
      float y2 = sv[c4*4+2]*acc[rr][c4*4+2] + bvv[c4*4+2];
      float y3 = sv[c4*4+3]*acc[rr][c4*4+3] + bvv[c4*4+3];
      if (act){ y0=mishf(y0); y1=mishf(y1); y2=mishf(y2); y3=mishf(y3); }
      *(float4*)&yr[c4*4] = make_float4(y0,y1,y2,y3);
    }
  }
}

// ---------------- edge gather + BN + mish + max over k ----------------
template<int O>
__global__ __launch_bounds__(256) void k_edgemax(
    const float* __restrict__ ua, const int* __restrict__ idx,
    const float* __restrict__ g, const float* __restrict__ bb,
    float* __restrict__ Y)
{
  constexpr int TPR = O/4;
  const int gt = blockIdx.x*256 + threadIdx.x;
  const int m  = gt / TPR;
  const int og = gt % TPR;
  if (m >= M_) return;
  const int base = m & ~(N_-1);
  const int P = 2*O;
  const float4 u0 = *(const float4*)&ua[(size_t)m*P + og*4];
  const float4 a0 = *(const float4*)&ua[(size_t)m*P + O + og*4];
  const float srs = rsqrtf(1.f + 1e-5f);
  const float4 gv  = *(const float4*)&g[og*4];
  const float4 bv4 = *(const float4*)&bb[og*4];
  const float sx = gv.x*srs, sy = gv.y*srs, sz = gv.z*srs, sw = gv.w*srs;
  const float cx = a0.x - u0.x, cy = a0.y - u0.y, cz = a0.z - u0.z, cw = a0.w - u0.w;
  float mx = -INFINITY, my = -INFINITY, mz = -INFINITY, mw = -INFINITY;
  const int* id = idx + (size_t)m*KNN;
#pragma unroll
  for (int k=0;k<KNN;k++){
    int j = id[k];
    const float4 uj = *(const float4*)&ua[(size_t)(base + j)*P + og*4];
    float zx = fmaf(sx, uj.x + cx, bv4.x);
    float zy = fmaf(sy, uj.y + cy, bv4.y);
    float zz = fmaf(sz, uj.z + cz, bv4.z);
    float zw = fmaf(sw, uj.w + cw, bv4.w);
    mx = fmaxf(mx, mishf(zx));
    my = fmaxf(my, mishf(zy));
    mz = fmaxf(mz, mishf(zz));
    mw = fmaxf(mw, mishf(zw));
  }
  *(float4*)&Y[(size_t)m*O + og*4] = make_float4(mx,my,mz,mw);
}

// ---------------- final projection: out(B,2,N) = W9 @ h8 ----------------
__global__ __launch_bounds__(256) void k_final(const float* __restrict__ h,
                                               const float* __restrict__ W9,
                                               float* __restrict__ out){
  __shared__ float w[128];
  const int t = threadIdx.x;
  if (t < 128) w[t] = W9[t];
  __syncthreads();
  const int m = blockIdx.x*256 + t;
  if (m >= M_) return;
  const int b = m >> 12, i = m & (N_-1);
  const float* hr = h + (size_t)m*64;
  float s0 = 0.f, s1 = 0.f;
#pragma unroll
  for (int c=0;c<64;c++){ float v = hr[c]; s0 = fmaf(w[c], v, s0); s1 = fmaf(w[64+c], v, s1); }
  out[((size_t)b*2 + 0)*N_ + i] = s0;
  out[((size_t)b*2 + 1)*N_ + i] = s1;
}

extern "C" void kernel_launch(void* const* d_in, const int* in_sizes, int n_in,
                              void* d_out, int out_size, void* d_ws, size_t ws_size,
                              hipStream_t stream)
{
  const float* x  = (const float*)d_in[0];
  const float* W1 = (const float*)d_in[1];
  const float* W2 = (const float*)d_in[2];
  const float* W3 = (const float*)d_in[3];
  const float* W4 = (const float*)d_in[4];
  const float* W5 = (const float*)d_in[5];
  const float* W6 = (const float*)d_in[6];
  const float* W7 = (const float*)d_in[7];
  const float* W8 = (const float*)d_in[8];
  const float* W9 = (const float*)d_in[9];
  const float* g1 = (const float*)d_in[10]; const float* b1 = (const float*)d_in[11];
  const float* g2 = (const float*)d_in[12]; const float* b2 = (const float*)d_in[13];
  const float* g3 = (const float*)d_in[14]; const float* b3 = (const float*)d_in[15];
  const float* g4 = (const float*)d_in[16]; const float* b4 = (const float*)d_in[17];
  const float* g5 = (const float*)d_in[18]; const float* b5 = (const float*)d_in[19];
  const float* g6 = (const float*)d_in[20]; const float* b6 = (const float*)d_in[21];
  const float* g7 = (const float*)d_in[22]; const float* b7 = (const float*)d_in[23];
  const float* g8 = (const float*)d_in[24]; const float* b8 = (const float*)d_in[25];
  float* out = (float*)d_out;

  float* ws  = (float*)d_ws;
  float* xp  = ws;                       // 98304
  float* xx  = xp + 98304;               // 32768
  int*   idx = (int*)(xx + 32768);       // 327680 ints
  float* ua  = (float*)(idx + 327680);   // 8388608 floats (max M*256)
  float* x1  = ua + 8388608;             // M*64
  float* x2  = x1 + 2097152;             // M*64
  float* x3  = x2 + 2097152;             // M*128
  float* h4  = x3 + 4194304;             // M*128
  float* h5  = h4 + 4194304;             // M*128
  float* h6  = x3;
  float* h7  = h4;
  float* h8  = h5;
  // bf16 split buffers alias the (currently dead) ua region during kNN
  ushort* Xhi = (ushort*)ua;             // M*64 ushorts = 1M floats
  ushort* Xlo = (ushort*)(ua + 1048576); // M*64 ushorts

  const dim3 blk(256);
  const float* nullf = nullptr;

  // ---- stage 1 (C=3 -> 64) ----
  k_transpose_x<<<dim3(M_/256), blk, 0, stream>>>(x, xp);
  k_xx<3><<<dim3(M_/256), blk, 0, stream>>>(xp, xx);
  k_knn<3><<<dim3(N_/64, B_), blk, 0, stream>>>(xp, xx, idx);
  k_gemm<128><<<dim3(M_/64, 1), blk, 0, stream>>>(xp, 3, nullf, 0,
      W1, 63, 6, 6, 3, nullf, nullf, 0, ua, 128);
  k_edgemax<64><<<dim3(M_*16/256), blk, 0, stream>>>(ua, idx, g1, b1, x1);

  // ---- stage 2 (64 -> 64) ----
  k_xx<64><<<dim3(M_/256), blk, 0, stream>>>(x1, xx);
  k_cvt<<<dim3(M_*64/(8*256)), blk, 0, stream>>>(x1, Xhi, Xlo);
  k_knn64m<<<dim3(512), blk, 0, stream>>>(Xhi, Xlo, xx, idx);
  k_gemm<128><<<dim3(M_/64, 1), blk, 0, stream>>>(x1, 64, nullf, 0,
      W2, 63, 6, 128, 64, nullf, nullf, 0, ua, 128);
  k_edgemax<64><<<dim3(M_*16/256), blk, 0, stream>>>(ua, idx, g2, b2, x2);

  // ---- stage 3 (64 -> 128) ----
  k_xx<64><<<dim3(M_/256), blk, 0, stream>>>(x2, xx);
  k_cvt<<<dim3(M_*64/(8*256)), blk, 0, stream>>>(x2, Xhi, Xlo);
  k_knn64m<<<dim3(512), blk, 0, stream>>>(Xhi, Xlo, xx, idx);
  k_gemm<128><<<dim3(M_/64, 2), blk, 0, stream>>>(x2, 64, nullf, 0,
      W3, 127, 7, 128, 64, nullf, nullf, 0, ua, 256);
  k_edgemax<128><<<dim3(M_*32/256), blk, 0, stream>>>(ua, idx, g3, b3, x3);

  // ---- MLP head ----
  k_gemm<128><<<dim3(M_/64, 1), blk, 0, stream>>>(x3, 128, nullf, 0,
      W4, 127, 7, 128, 0, g4, b4, 1, h4, 128);
  k_gemm<128><<<dim3(M_/64, 1), blk, 0, stream>>>(h4, 128, x3, 128,
      W5, 127, 7, 256, 0, g5, b5, 1, h5, 128);
  k_gemm<64><<<dim3(M_/64, 1), blk, 0, stream>>>(h5, 128, nullf, 0,
      W6, 63, 6, 128, 0, g6, b6, 1, h6, 64);
  k_gemm<64><<<dim3(M_/64, 1), blk, 0, stream>>>(h6, 64, x2, 64,
      W7, 63, 6, 128, 0, g7, b7, 1, h7, 64);
  k_gemm<64><<<dim3(M_/64, 1), blk, 0, stream>>>(h7, 64, x1, 64,
      W8, 63, 6, 128, 0, g8, b8, 1, h8, 64);
  k_final<<<dim3(M_/256), blk, 0, stream>>>(h8, W9, out);
}